// Round 5
// baseline (14410.567 us; speedup 1.0000x reference)
//
#include <hip/hip_runtime.h>

// VoiceModel: 2 branches x { scalar-LSTM(1->1,L2) over T=512 per (b,class),
// then LSTM(1->256,L2) over 128 class-steps }, concat -> MLP(512->200->128).
// Round 5: weight slices LDS-resident (q=16 N-split, 32 KB/block), 512 blocks
// co-resident (2/CU), wave=gate decomposition, round-3 exchange protocol.

typedef _Float16 f16;
typedef __attribute__((ext_vector_type(4))) _Float16 f16x4;
typedef __attribute__((ext_vector_type(8))) _Float16 f16x8;
typedef __attribute__((ext_vector_type(4))) float f32x4;

#define NBATCH 256
#define NTIME  512
#define NCLS   128
#define NHID   256

__device__ __forceinline__ float sigf(float x) {
    return __builtin_amdgcn_rcpf(1.0f + __expf(-x));
}
__device__ __forceinline__ float tanh_f(float x) {
    return fmaf(2.0f, __builtin_amdgcn_rcpf(1.0f + __expf(-2.0f * x)), -1.0f);
}
__device__ __forceinline__ f16x4 LO(f16x8 v) { f16x4 r; r[0]=v[0]; r[1]=v[1]; r[2]=v[2]; r[3]=v[3]; return r; }
__device__ __forceinline__ f16x4 HI(f16x8 v) { f16x4 r; r[0]=v[4]; r[1]=v[5]; r[2]=v[6]; r[3]=v[7]; return r; }

// ---------------- K0: convert + swizzle 6 weight matrices (1024x256) to f16 --
// layout per matrix: elem ((g*16+f)*8+ktp)*512 + l*8 + e   (l = lane = fq*16+fr)
//   = W[g*256 + f*16 + fr][ktp*32 + (e>>2)*16 + fq*4 + (e&3)]
struct P6 {
    const float* s0; const float* s1; const float* s2;
    const float* s3; const float* s4; const float* s5;
};

__global__ __launch_bounds__(256) void k_cvt(P6 p, f16* __restrict__ dst) {
    int i = blockIdx.x * 256 + threadIdx.x;      // 6 * 262144 total
    int seg = i >> 18, d = i & 262143;
    const float* s = seg == 0 ? p.s0 : seg == 1 ? p.s1 : seg == 2 ? p.s2
                   : seg == 3 ? p.s3 : seg == 4 ? p.s4 : p.s5;
    const int e  = d & 7;
    const int fr = (d >> 3) & 15;
    const int fq = (d >> 7) & 3;
    const int ktp = (d >> 9) & 7;
    const int f  = (d >> 12) & 15;
    const int g  = (d >> 16) & 3;
    const int row = g * 256 + f * 16 + fr;
    const int col = ktp * 32 + (e >> 2) * 16 + fq * 4 + (e & 3);
    dst[i] = (f16)s[row * 256 + col];
}

// ---------------- zero the exchange flags (every call; graph-replay safe) ----
__global__ void k_zero(int* __restrict__ f) { f[threadIdx.x] = 0; }

// ---------------- K1: scalar 2-layer LSTM per (branch, b, class) -------------
__global__ __launch_bounds__(128) void k_scalar_lstm(
    const int* __restrict__ ln, const int* __restrict__ rn,
    const float* __restrict__ tlW, const float* __restrict__ tlU, const float* __restrict__ tlb,
    const float* __restrict__ trW, const float* __restrict__ trU, const float* __restrict__ trb,
    float* __restrict__ states)
{
    __shared__ int tok[NTIME];
    const int bid = blockIdx.x;
    const int branch = bid >> 8;
    const int b = bid & 255;
    const int* tp = (branch ? rn : ln) + (size_t)b * (4 * NTIME);  // voice 0
    for (int i = threadIdx.x; i < NTIME; i += 128) tok[i] = tp[i];
    __syncthreads();
    const float* W  = branch ? trW : tlW;
    const float* U  = branch ? trU : tlU;
    const float* Bb = branch ? trb : tlb;
    const float u00 = U[0], u01 = U[1], u02 = U[2], u03 = U[3];
    const float f00 = Bb[0], f01 = Bb[1], f02 = Bb[2], f03 = Bb[3];
    const float o00 = f00 + W[0], o01 = f01 + W[1], o02 = f02 + W[2], o03 = f03 + W[3];
    const float w10 = W[4], w11 = W[5], w12 = W[6], w13 = W[7];
    const float u10 = U[4], u11 = U[5], u12 = U[6], u13 = U[7];
    const float b10 = Bb[4], b11 = Bb[5], b12 = Bb[6], b13 = Bb[7];
    const int n = threadIdx.x;
    float h0 = 0.f, c0 = 0.f, h1 = 0.f, c1 = 0.f;
    for (int t = 0; t < NTIME; ++t) {
        const bool x = (tok[t] == n);
        float pi = fmaf(u00, h0, x ? o00 : f00);
        float pf = fmaf(u01, h0, x ? o01 : f01);
        float pg = fmaf(u02, h0, x ? o02 : f02);
        float po = fmaf(u03, h0, x ? o03 : f03);
        float ig = sigf(pi), fg = sigf(pf), gg = tanh_f(pg), og = sigf(po);
        c0 = fmaf(fg, c0, ig * gg);
        h0 = og * tanh_f(c0);
        pi = fmaf(w10, h0, fmaf(u10, h1, b10));
        pf = fmaf(w11, h0, fmaf(u11, h1, b11));
        pg = fmaf(w12, h0, fmaf(u12, h1, b12));
        po = fmaf(w13, h0, fmaf(u13, h1, b13));
        ig = sigf(pi); fg = sigf(pf); gg = tanh_f(pg); og = sigf(po);
        c1 = fmaf(fg, c1, ig * gg);
        h1 = og * tanh_f(c1);
    }
    states[((size_t)(branch * NBATCH + b)) * NCLS + n] = h1;
}

// ---------------- K2: layer-0 recurrence ---------------------------------------
// grid 512 = q(16)*32 + group(32). 256 thr = 4 waves; wave w = gate w.
// Block owns hidden frag q (16 units, 4 gates): Whh slice 32 KB in LDS.
// h image 16x256 in LDS; per step: 512B own chunk -> h0img[group][t] (exchange
// medium AND layer-1 input), flag release, spin 15 peers, gather 7.5 KB.
__global__ __launch_bounds__(256, 2) void k_rec0(
    const float* __restrict__ states,
    const f16* __restrict__ whh0,
    const float* __restrict__ wih0L, const float* __restrict__ wih0R,
    const float* __restrict__ bL, const float* __restrict__ bR,
    f16* __restrict__ h0img,               // [32 group][128 t][4096]
    int* __restrict__ flags)               // [32 group][16]
{
    __shared__ f16 wlds[16384];            // 32 KB: [(g*8+ktp)][512]
    __shared__ f16 img[4096];              // 8 KB h fragment image
    __shared__ float lst[16 * NCLS];       // 8 KB
    __shared__ float cmb[3][256];          // 3 KB pre-acts from waves 1..3
    const int bid = blockIdx.x;
    const int q = bid >> 5, group = bid & 31;
    const int branch = group >> 4, tb = group & 15;
    const int tid = threadIdx.x;
    const int w = tid >> 6, l = tid & 63, fr = l & 15, fq = l >> 4;

    {   // stage weight slice: rows (g, f=q), g=0..3 -> 2048 x 16B
        const f16* base = whh0 + ((size_t)branch << 18);
        for (int c = tid; c < 2048; c += 256) {
            const int rowL = c >> 6, coli = c & 63;       // rowL = g*8+ktp
            const int g = rowL >> 3, ktp = rowL & 7;
            *(uint4*)(wlds + (size_t)c * 8) =
                *(const uint4*)(base + ((size_t)((g * 16 + q) * 8 + ktp) << 9) + coli * 8);
        }
    }
    for (int i = tid; i < 16 * NCLS; i += 256)
        lst[i] = states[((size_t)(branch * NBATCH + tb * 16 + (i >> 7))) * NCLS + (i & 127)];
    ((uint4*)img)[tid] = (uint4){0u, 0u, 0u, 0u};
    ((uint4*)img)[tid + 256] = (uint4){0u, 0u, 0u, 0u};

    const float* bias = branch ? bR : bL;
    const float* w0   = branch ? wih0R : wih0L;
    float bv[4], w0v[4];
#pragma unroll
    for (int g = 0; g < 4; ++g) {
        const int row = g * 256 + q * 16 + fr;
        bv[g] = bias[row];
        w0v[g] = w0[row];
    }
    float cst[4] = {0.f, 0.f, 0.f, 0.f};
    f16* gimg = h0img + (size_t)group * (NCLS * 4096);
    int* flg = flags + group * 16;
    __syncthreads();

    for (int t = 0; t < NCLS; ++t) {
        f16x4 af[16];
#pragma unroll
        for (int kt = 0; kt < 16; ++kt)
            af[kt] = *(const f16x4*)(img + kt * 256 + l * 4);
        f32x4 a0 = {0.f, 0.f, 0.f, 0.f}, a1 = {0.f, 0.f, 0.f, 0.f};
#pragma unroll
        for (int ktp = 0; ktp < 8; ++ktp) {
            const f16x8 v = *(const f16x8*)(wlds + ((w * 8 + ktp) << 9) + l * 8);
            a0 = __builtin_amdgcn_mfma_f32_16x16x16f16(af[2 * ktp],     LO(v), a0, 0, 0, 0);
            a1 = __builtin_amdgcn_mfma_f32_16x16x16f16(af[2 * ktp + 1], HI(v), a1, 0, 0, 0);
        }
        const f32x4 acc = a0 + a1;
        if (w > 0) *(f32x4*)&cmb[w - 1][l * 4] = acc;
        __syncthreads();                    // cmb ready; img af-reads done
        if (w == 0) {
#pragma unroll
            for (int r = 0; r < 4; ++r) {
                const int li = l * 4 + r;
                const float st = lst[(fq * 4 + r) * NCLS + t];
                const float pi = fmaf(st, w0v[0], acc[r] + bv[0]);
                const float pf = fmaf(st, w0v[1], cmb[0][li] + bv[1]);
                const float pg = fmaf(st, w0v[2], cmb[1][li] + bv[2]);
                const float po = fmaf(st, w0v[3], cmb[2][li] + bv[3]);
                const float ig = sigf(pi), fg = sigf(pf), gg = tanh_f(pg), og = sigf(po);
                cst[r] = fmaf(fg, cst[r], ig * gg);
                const float hn = og * tanh_f(cst[r]);
                img[q * 256 + (fq * 4 + r + 16 * (fr >> 2)) * 4 + (fr & 3)] = (f16)hn;
            }
        }
        __syncthreads();                    // own 512B chunk complete in LDS
        f16* gdst = gimg + (size_t)t * 4096;
        if (tid < 64)
            ((uint2*)gdst)[q * 64 + tid] = ((const uint2*)img)[q * 64 + tid];
        if (t == NCLS - 1) break;
        __syncthreads();                    // drains vmcnt: chunk store done
        __threadfence();
        if (tid == 0)
            __hip_atomic_store(&flg[q], t + 1, __ATOMIC_RELEASE, __HIP_MEMORY_SCOPE_AGENT);
        if (tid < 15) {
            const int p = tid + (tid >= q);
            while (__hip_atomic_load(&flg[p], __ATOMIC_ACQUIRE, __HIP_MEMORY_SCOPE_AGENT) <= t)
                __builtin_amdgcn_s_sleep(2);
        }
        __syncthreads();                    // peers ready
        {
            uint2 tmp[4]; int n = 0;
#pragma unroll
            for (int j = w; j < 15; j += 4) {
                const int p = j + (j >= q);
                tmp[n++] = ((const uint2*)gdst)[p * 64 + l];
            }
            n = 0;
#pragma unroll
            for (int j = w; j < 15; j += 4) {
                const int p = j + (j >= q);
                ((uint2*)img)[p * 64 + l] = tmp[n++];
            }
        }
        __syncthreads();                    // img(t) complete
    }
}

// ---------------- K3: layer-1 recurrence ---------------------------------------
// grid 512 = q(16)*32 + group(32). 512 thr = 8 waves: w<4 recurrent (gate w,
// Whh1 slice in LDS), w>=4 input path (gate w-4, Wih1 slice streamed L1/L2,
// h0 image prefetched into LDS during previous step's exchange).
__global__ __launch_bounds__(512, 4) void k_rec1(
    const f16* __restrict__ whh1,
    const f16* __restrict__ wih1,
    const f16* __restrict__ h0img,         // [32][128][4096]
    const float* __restrict__ bL, const float* __restrict__ bR,
    f16* __restrict__ ring,                // [32 group][4 slot][4096]
    int* __restrict__ flags,               // [32 group][16]
    float* __restrict__ h1out)             // [2][256][256] f32
{
    __shared__ f16 wlds[16384];            // 32 KB Whh1 slice
    __shared__ f16 img[4096];              // 8 KB h1 image
    __shared__ f16 img2[4096];             // 8 KB h0[t] image (prefetched)
    __shared__ float cmb[7][256];          // 7 KB pre-acts
    const int bid = blockIdx.x;
    const int q = bid >> 5, group = bid & 31;
    const int branch = group >> 4, tb = group & 15;
    const int tid = threadIdx.x;
    const int w = tid >> 6, l = tid & 63, fr = l & 15, fq = l >> 4;
    const int g = w & 3, isIn = w >> 2;

    {   // stage Whh1 slice
        const f16* base = whh1 + ((size_t)branch << 18);
        for (int c = tid; c < 2048; c += 512) {
            const int rowL = c >> 6, coli = c & 63;
            const int gg = rowL >> 3, ktp = rowL & 7;
            *(uint4*)(wlds + (size_t)c * 8) =
                *(const uint4*)(base + ((size_t)((gg * 16 + q) * 8 + ktp) << 9) + coli * 8);
        }
    }
    const f16* gimg = h0img + (size_t)group * (NCLS * 4096);
    ((uint4*)img)[tid] = (uint4){0u, 0u, 0u, 0u};
    ((uint4*)img2)[tid] = ((const uint4*)gimg)[tid];   // prefetch h0[0]

    const float* bias = branch ? bR : bL;
    float bv[4];
#pragma unroll
    for (int gg = 0; gg < 4; ++gg) bv[gg] = bias[gg * 256 + q * 16 + fr];
    const f16* wib = wih1 + ((size_t)branch << 18) + l * 8;  // per-lane stream base
    float cst[4] = {0.f, 0.f, 0.f, 0.f};
    f16* gring = ring + (size_t)group * (4 * 4096);
    int* flg = flags + group * 16;
    __syncthreads();

    for (int t = 0; t < NCLS; ++t) {
        f16x4 af[16];
        if (isIn) {
#pragma unroll
            for (int kt = 0; kt < 16; ++kt)
                af[kt] = *(const f16x4*)(img2 + kt * 256 + l * 4);
        } else {
#pragma unroll
            for (int kt = 0; kt < 16; ++kt)
                af[kt] = *(const f16x4*)(img + kt * 256 + l * 4);
        }
        f32x4 a0 = {0.f, 0.f, 0.f, 0.f}, a1 = {0.f, 0.f, 0.f, 0.f};
#pragma unroll
        for (int ktp = 0; ktp < 8; ++ktp) {
            f16x8 v;
            if (isIn) v = *(const f16x8*)(wib + ((size_t)((g * 16 + q) * 8 + ktp) << 9));
            else      v = *(const f16x8*)(wlds + ((g * 8 + ktp) << 9) + l * 8);
            a0 = __builtin_amdgcn_mfma_f32_16x16x16f16(af[2 * ktp],     LO(v), a0, 0, 0, 0);
            a1 = __builtin_amdgcn_mfma_f32_16x16x16f16(af[2 * ktp + 1], HI(v), a1, 0, 0, 0);
        }
        const f32x4 acc = a0 + a1;
        if (w > 0) *(f32x4*)&cmb[w - 1][l * 4] = acc;
        __syncthreads();                    // cmb ready; img af-reads done
        if (w == 0) {
#pragma unroll
            for (int r = 0; r < 4; ++r) {
                const int li = l * 4 + r;
                const float pi = acc[r]     + cmb[3][li] + bv[0];
                const float pf = cmb[0][li] + cmb[4][li] + bv[1];
                const float pg = cmb[1][li] + cmb[5][li] + bv[2];
                const float po = cmb[2][li] + cmb[6][li] + bv[3];
                const float ig = sigf(pi), fg = sigf(pf), gg = tanh_f(pg), og = sigf(po);
                cst[r] = fmaf(fg, cst[r], ig * gg);
                const float hn = og * tanh_f(cst[r]);
                if (t == NCLS - 1)
                    h1out[((size_t)(branch * NBATCH + tb * 16 + fq * 4 + r)) * NHID
                          + q * 16 + fr] = hn;
                else
                    img[q * 256 + (fq * 4 + r + 16 * (fr >> 2)) * 4 + (fr & 3)] = (f16)hn;
            }
        }
        if (t == NCLS - 1) break;
        __syncthreads();                    // own chunk complete in LDS
        f16* gdst = gring + (size_t)(t & 3) * 4096;
        if (tid < 64)
            ((uint2*)gdst)[q * 64 + tid] = ((const uint2*)img)[q * 64 + tid];
        __syncthreads();                    // drains vmcnt: chunk store done
        __threadfence();
        if (tid == 0)
            __hip_atomic_store(&flg[q], t + 1, __ATOMIC_RELEASE, __HIP_MEMORY_SCOPE_AGENT);
        if (tid < 15) {
            const int p = tid + (tid >= q);
            while (__hip_atomic_load(&flg[p], __ATOMIC_ACQUIRE, __HIP_MEMORY_SCOPE_AGENT) <= t)
                __builtin_amdgcn_s_sleep(2);
        }
        __syncthreads();                    // peers ready
        {
            uint2 tmp[2]; int n = 0;
#pragma unroll
            for (int j = w; j < 15; j += 8) {
                const int p = j + (j >= q);
                tmp[n++] = ((const uint2*)gdst)[p * 64 + l];
            }
            const uint4 pf4 = ((const uint4*)(gimg + (size_t)(t + 1) * 4096))[tid];
            n = 0;
#pragma unroll
            for (int j = w; j < 15; j += 8) {
                const int p = j + (j >= q);
                ((uint2*)img)[p * 64 + l] = tmp[n++];
            }
            ((uint4*)img2)[tid] = pf4;      // h0[t+1] prefetch lands
        }
        __syncthreads();                    // img(t) + img2(t+1) complete
    }
}

// ---------------- K4: MLP head (2H -> 200 -> 128), f32 ------------------------
__global__ __launch_bounds__(256) void k_mlp(
    const float* __restrict__ h1all,   // [2][256][256]
    const float* __restrict__ W1, const float* __restrict__ b1,
    const float* __restrict__ W2, const float* __restrict__ b2,
    float* __restrict__ out)
{
    __shared__ float hrow[512];
    __shared__ float hid[200];
    const int b = blockIdx.x, tid = threadIdx.x;
    hrow[tid]       = h1all[(size_t)b * NHID + tid];
    hrow[256 + tid] = h1all[(size_t)(NBATCH + b) * NHID + tid];
    __syncthreads();
    if (tid < 200) {
        float a = b1[tid];
        const float* wr = W1 + (size_t)tid * 512;
        for (int k = 0; k < 512; ++k) a = fmaf(wr[k], hrow[k], a);
        hid[tid] = fmaxf(a, 0.f);
    }
    __syncthreads();
    if (tid < 128) {
        float a = b2[tid];
        const float* wr = W2 + (size_t)tid * 200;
        for (int j = 0; j < 200; ++j) a = fmaf(wr[j], hid[j], a);
        out[(size_t)b * 128 + tid] = a;
    }
}

// ---------------- launch ------------------------------------------------------
extern "C" void kernel_launch(void* const* d_in, const int* in_sizes, int n_in,
                              void* d_out, int out_size, void* d_ws, size_t ws_size,
                              hipStream_t stream)
{
    (void)in_sizes; (void)n_in; (void)out_size; (void)ws_size;
    const int*   ln    = (const int*)d_in[0];
    const int*   rn    = (const int*)d_in[2];
    const float* tlW   = (const float*)d_in[4];
    const float* tlU   = (const float*)d_in[5];
    const float* tlb   = (const float*)d_in[6];
    const float* trW   = (const float*)d_in[7];
    const float* trU   = (const float*)d_in[8];
    const float* trb   = (const float*)d_in[9];
    const float* wih0L = (const float*)d_in[10];
    const float* b0L   = (const float*)d_in[12];
    const float* b1L   = (const float*)d_in[15];
    const float* wih0R = (const float*)d_in[16];
    const float* b0R   = (const float*)d_in[18];
    const float* b1R   = (const float*)d_in[21];
    const float* mW1   = (const float*)d_in[22];
    const float* mb1   = (const float*)d_in[23];
    const float* mW2   = (const float*)d_in[24];
    const float* mb2   = (const float*)d_in[25];

    // workspace layout (bytes)
    char* ws = (char*)d_ws;
    f16*   w16    = (f16*)ws;                        // 3 MB swizzled weights
    float* states = (float*)(ws + 3145728);          // 256 KB
    float* h1out  = (float*)(ws + 3407872);          // 512 KB
    int*   flags  = (int*)(ws + 3932160);            // 1024 ints
    f16*   h1ring = (f16*)(ws + 3936256);            // 1 MB
    f16*   h0img  = (f16*)(ws + 4984832);            // 32 MB

    f16* whh0 = w16;
    f16* whh1 = w16 + 2 * 262144;
    f16* wih1 = w16 + 4 * 262144;
    int* flags0 = flags;
    int* flags1 = flags + 512;

    P6 p { (const float*)d_in[11], (const float*)d_in[17],   // nl_Whh0, nr_Whh0
           (const float*)d_in[14], (const float*)d_in[20],   // nl_Whh1, nr_Whh1
           (const float*)d_in[13], (const float*)d_in[19] }; // nl_Wih1, nr_Wih1
    k_zero<<<1, 1024, 0, stream>>>(flags);
    k_cvt<<<6144, 256, 0, stream>>>(p, w16);
    k_scalar_lstm<<<512, 128, 0, stream>>>(ln, rn, tlW, tlU, tlb, trW, trU, trb, states);
    k_rec0<<<512, 256, 0, stream>>>(states, whh0, wih0L, wih0R, b0L, b0R, h0img, flags0);
    k_rec1<<<512, 512, 0, stream>>>(whh1, wih1, h0img, b1L, b1R, h1ring, flags1, h1out);
    k_mlp<<<256, 256, 0, stream>>>(h1out, mW1, mb1, mW2, mb2, (float*)d_out);
}

// Round 6
// 2017.915 us; speedup vs baseline: 7.1413x; 7.1413x over previous
//
#include <hip/hip_runtime.h>

// VoiceModel: 2 branches x { scalar-LSTM(1->1,L2) over T=512 per (b,class),
// then LSTM(1->256,L2) over 128 class-steps }, concat -> MLP(512->200->128).
// Round 6: 8-way hidden split, BOTH weight slices LDS-resident (dynamic LDS),
// XCD-co-located exchange groups, padded per-member flags (256B), wave-0
// release with inline vmcnt(0), coprime-stride cmb (no bank conflicts),
// rec1 input path fed by register-prefetched h0 frags (no serial L2 stream).

typedef _Float16 f16;
typedef __attribute__((ext_vector_type(4))) _Float16 f16x4;
typedef __attribute__((ext_vector_type(8))) _Float16 f16x8;
typedef __attribute__((ext_vector_type(4))) float f32x4;

#define NBATCH 256
#define NTIME  512
#define NCLS   128
#define NHID   256

__device__ __forceinline__ float sigf(float x) {
    return __builtin_amdgcn_rcpf(1.0f + __expf(-x));
}
__device__ __forceinline__ float tanh_f(float x) {
    return fmaf(2.0f, __builtin_amdgcn_rcpf(1.0f + __expf(-2.0f * x)), -1.0f);
}
__device__ __forceinline__ f16x4 LO(f16x8 v) { f16x4 r; r[0]=v[0]; r[1]=v[1]; r[2]=v[2]; r[3]=v[3]; return r; }
__device__ __forceinline__ f16x4 HI(f16x8 v) { f16x4 r; r[0]=v[4]; r[1]=v[5]; r[2]=v[6]; r[3]=v[7]; return r; }

// ---------------- K0: convert + swizzle 6 weight matrices (1024x256) to f16 --
// layout per matrix: elem ((g*16+fi)*8+ktp)*512 + l*8 + e   (l = lane)
//   = W[g*256 + fi*16 + fr][ktp*32 + (e>>2)*16 + fq*4 + (e&3)]
struct P6 {
    const float* s0; const float* s1; const float* s2;
    const float* s3; const float* s4; const float* s5;
};

__global__ __launch_bounds__(256) void k_cvt(P6 p, f16* __restrict__ dst) {
    int i = blockIdx.x * 256 + threadIdx.x;      // 6 * 262144 total
    int seg = i >> 18, d = i & 262143;
    const float* s = seg == 0 ? p.s0 : seg == 1 ? p.s1 : seg == 2 ? p.s2
                   : seg == 3 ? p.s3 : seg == 4 ? p.s4 : p.s5;
    const int e  = d & 7;
    const int fr = (d >> 3) & 15;
    const int fq = (d >> 7) & 3;
    const int ktp = (d >> 9) & 7;
    const int fi = (d >> 12) & 15;
    const int g  = (d >> 16) & 3;
    const int row = g * 256 + fi * 16 + fr;
    const int col = ktp * 32 + (e >> 2) * 16 + fq * 4 + (e & 3);
    dst[i] = (f16)s[row * 256 + col];
}

// ---------------- zero the exchange flags (every call; graph-replay safe) ----
__global__ void k_zero(int* __restrict__ f) { f[blockIdx.x * 1024 + threadIdx.x] = 0; }

// ---------------- K1: scalar 2-layer LSTM per (branch, b, class) -------------
__global__ __launch_bounds__(128) void k_scalar_lstm(
    const int* __restrict__ ln, const int* __restrict__ rn,
    const float* __restrict__ tlW, const float* __restrict__ tlU, const float* __restrict__ tlb,
    const float* __restrict__ trW, const float* __restrict__ trU, const float* __restrict__ trb,
    float* __restrict__ states)
{
    __shared__ int tok[NTIME];
    const int bid = blockIdx.x;
    const int branch = bid >> 8;
    const int b = bid & 255;
    const int* tp = (branch ? rn : ln) + (size_t)b * (4 * NTIME);  // voice 0
    for (int i = threadIdx.x; i < NTIME; i += 128) tok[i] = tp[i];
    __syncthreads();
    const float* W  = branch ? trW : tlW;
    const float* U  = branch ? trU : tlU;
    const float* Bb = branch ? trb : tlb;
    const float u00 = U[0], u01 = U[1], u02 = U[2], u03 = U[3];
    const float f00 = Bb[0], f01 = Bb[1], f02 = Bb[2], f03 = Bb[3];
    const float o00 = f00 + W[0], o01 = f01 + W[1], o02 = f02 + W[2], o03 = f03 + W[3];
    const float w10 = W[4], w11 = W[5], w12 = W[6], w13 = W[7];
    const float u10 = U[4], u11 = U[5], u12 = U[6], u13 = U[7];
    const float b10 = Bb[4], b11 = Bb[5], b12 = Bb[6], b13 = Bb[7];
    const int n = threadIdx.x;
    float h0 = 0.f, c0 = 0.f, h1 = 0.f, c1 = 0.f;
    for (int t = 0; t < NTIME; ++t) {
        const bool x = (tok[t] == n);
        float pi = fmaf(u00, h0, x ? o00 : f00);
        float pf = fmaf(u01, h0, x ? o01 : f01);
        float pg = fmaf(u02, h0, x ? o02 : f02);
        float po = fmaf(u03, h0, x ? o03 : f03);
        float ig = sigf(pi), fg = sigf(pf), gg = tanh_f(pg), og = sigf(po);
        c0 = fmaf(fg, c0, ig * gg);
        h0 = og * tanh_f(c0);
        pi = fmaf(w10, h0, fmaf(u10, h1, b10));
        pf = fmaf(w11, h0, fmaf(u11, h1, b11));
        pg = fmaf(w12, h0, fmaf(u12, h1, b12));
        po = fmaf(w13, h0, fmaf(u13, h1, b13));
        ig = sigf(pi); fg = sigf(pf); gg = tanh_f(pg); og = sigf(po);
        c1 = fmaf(fg, c1, ig * gg);
        h1 = og * tanh_f(c1);
    }
    states[((size_t)(branch * NBATCH + b)) * NCLS + n] = h1;
}

// ---------------- K2: layer-0 recurrence, 8-way split, LDS weights -----------
// grid 256: blockIdx = group(32) + 32*member(8) -> members XCD-co-located.
// Block owns hidden units [qm*32, qm*32+32), all 4 gates (128 rows): 64 KB LDS.
// 4 waves = 4 gates; waves 0,1 finish frags 0,1. Exchange: 1 KB chunk,
// padded flags (256 B/member), wave-0 release with inline vmcnt(0).
__global__ __launch_bounds__(256, 1) void k_rec0(
    const float* __restrict__ states,
    const f16* __restrict__ whh0,
    const float* __restrict__ wih0L, const float* __restrict__ wih0R,
    const float* __restrict__ bL, const float* __restrict__ bR,
    f16* __restrict__ h0img,               // [32 group][128 t][4096]
    int* __restrict__ flags)               // [32 group][8 member] stride 64 ints
{
    extern __shared__ char smem[];
    f16*   wlds = (f16*)smem;                    // 65536 B
    f16*   img  = (f16*)(smem + 65536);          // 8192 B
    float* lst  = (float*)(smem + 73728);        // 8192 B
    float* cmb  = (float*)(smem + 81920);        // 10240 B (stride-5 floats)

    const int qm = blockIdx.x >> 5, g = blockIdx.x & 31;
    const int branch = g >> 4, tb = g & 15;
    const int tid = threadIdx.x;
    const int w = tid >> 6, l = tid & 63, fr = l & 15, fq = l >> 4;

    {   // stage Whh0 slice: 64 rows (g2*2+f)*8+ktp of 512 f16
        const f16* base = whh0 + ((size_t)branch << 18);
        for (int c = tid; c < 4096; c += 256) {
            const int rl = c >> 6, coli = c & 63;
            const int gg = rl >> 4, f = (rl >> 3) & 1, ktp = rl & 7;
            *(uint4*)(wlds + rl * 512 + coli * 8) =
                *(const uint4*)(base + ((size_t)((gg * 16 + qm * 2 + f) * 8 + ktp) << 9) + coli * 8);
        }
    }
    for (int i = tid; i < 16 * NCLS; i += 256)
        lst[i] = states[((size_t)(branch * NBATCH + tb * 16 + (i >> 7))) * NCLS + (i & 127)];
    ((uint4*)img)[tid] = (uint4){0u, 0u, 0u, 0u};
    ((uint4*)img)[tid + 256] = (uint4){0u, 0u, 0u, 0u};

    const float* bias = branch ? bR : bL;
    const float* w0p  = branch ? wih0R : wih0L;
    const int ubase = qm * 32 + (w < 2 ? w : 0) * 16 + fr;
    float bv[4], w0v[4];
#pragma unroll
    for (int g4 = 0; g4 < 4; ++g4) {
        bv[g4]  = bias[g4 * 256 + ubase];
        w0v[g4] = w0p[g4 * 256 + ubase];
    }
    float cst[4] = {0.f, 0.f, 0.f, 0.f};
    f16* gimg = h0img + (size_t)g * (NCLS * 4096);
    int* flgb = flags + g * 8 * 64;
    __syncthreads();

    for (int t = 0; t < NCLS; ++t) {
        f16x4 af[16];
#pragma unroll
        for (int kt = 0; kt < 16; ++kt)
            af[kt] = *(const f16x4*)(img + kt * 256 + l * 4);
        f32x4 acc[2];
#pragma unroll
        for (int f = 0; f < 2; ++f) {
            f32x4 a0 = {0.f,0.f,0.f,0.f}, a1 = {0.f,0.f,0.f,0.f};
#pragma unroll
            for (int ktp = 0; ktp < 8; ++ktp) {
                const f16x8 v = *(const f16x8*)(wlds + (((w * 2 + f) * 8 + ktp) << 9) + l * 8);
                a0 = __builtin_amdgcn_mfma_f32_16x16x16f16(af[2 * ktp],     LO(v), a0, 0, 0, 0);
                a1 = __builtin_amdgcn_mfma_f32_16x16x16f16(af[2 * ktp + 1], HI(v), a1, 0, 0, 0);
            }
            acc[f] = a0 + a1;
        }
#pragma unroll
        for (int f = 0; f < 2; ++f)
#pragma unroll
            for (int r = 0; r < 4; ++r)
                cmb[((f * 4 + r) * 64 + l) * 5 + w] = acc[f][r];
        __syncthreads();                    // cmb ready; img af-reads done
        if (w < 2) {                        // finisher: frag f = w
#pragma unroll
            for (int r = 0; r < 4; ++r) {
                const int ci = ((w * 4 + r) * 64 + l) * 5;
                const float st = lst[(fq * 4 + r) * NCLS + t];
                const float pi = fmaf(st, w0v[0], cmb[ci + 0] + bv[0]);
                const float pf = fmaf(st, w0v[1], cmb[ci + 1] + bv[1]);
                const float pg = fmaf(st, w0v[2], cmb[ci + 2] + bv[2]);
                const float po = fmaf(st, w0v[3], cmb[ci + 3] + bv[3]);
                const float ig = sigf(pi), fg = sigf(pf), gg = tanh_f(pg), og = sigf(po);
                cst[r] = fmaf(fg, cst[r], ig * gg);
                const float hn = og * tanh_f(cst[r]);
                img[(qm * 2 + w) * 256 + (fq * 4 + r + 16 * (fr >> 2)) * 4 + (fr & 3)] = (f16)hn;
            }
        }
        __syncthreads();                    // own 1 KB chunk complete in LDS
        if (w == 0) {                       // wave 0 copies chunk to global
            uint2* gd = (uint2*)(gimg + (size_t)t * 4096);
            gd[qm * 128 + l]      = ((const uint2*)img)[qm * 128 + l];
            gd[qm * 128 + 64 + l] = ((const uint2*)img)[qm * 128 + 64 + l];
        }
        if (t == NCLS - 1) break;
        if (w == 0) {
            asm volatile("s_waitcnt vmcnt(0)" ::: "memory");
            if (l == 0)
                __hip_atomic_store(flgb + qm * 64, t + 1, __ATOMIC_RELEASE, __HIP_MEMORY_SCOPE_AGENT);
            if (l < 7) {
                const int p = l + (l >= qm);
                while (__hip_atomic_load(flgb + p * 64, __ATOMIC_ACQUIRE, __HIP_MEMORY_SCOPE_AGENT) <= t)
                    __builtin_amdgcn_s_sleep(1);
            }
        }
        __syncthreads();                    // peers ready
        if (tid < 128) {
            const uint2* gs = (const uint2*)(gimg + (size_t)t * 4096);
            uint2 tmp[7];
#pragma unroll
            for (int j = 0; j < 7; ++j) {
                const int p = j + (j >= qm);
                tmp[j] = gs[p * 128 + tid];
            }
#pragma unroll
            for (int j = 0; j < 7; ++j) {
                const int p = j + (j >= qm);
                ((uint2*)img)[p * 128 + tid] = tmp[j];
            }
        }
        __syncthreads();                    // img(t) complete
    }
}

// ---------------- K3: layer-1 recurrence, 8-way split, both weights in LDS ----
// grid 256 (same mapping), 512 thr = 8 waves: role = w>>2 (0 rec / 1 input),
// gate = w&3. Input waves register-prefetch h0(t+1) frags during exchange.
__global__ __launch_bounds__(512, 1) void k_rec1(
    const f16* __restrict__ whh1,
    const f16* __restrict__ wih1,
    const f16* __restrict__ h0img,         // [32][128][4096]
    const float* __restrict__ bL, const float* __restrict__ bR,
    f16* __restrict__ ring,                // [32 group][4 slot][4096]
    int* __restrict__ flags,               // [32 group][8] stride 64 ints
    float* __restrict__ h1out)             // [2][256][256] f32
{
    extern __shared__ char smem[];
    f16*   wldsA = (f16*)smem;                   // 65536 B (Whh1)
    f16*   wldsB = (f16*)(smem + 65536);         // 65536 B (Wih1)
    f16*   img   = (f16*)(smem + 131072);        // 8192 B
    float* cmb   = (float*)(smem + 139264);      // 18432 B (stride-9 floats)

    const int qm = blockIdx.x >> 5, g = blockIdx.x & 31;
    const int branch = g >> 4, tb = g & 15;
    const int tid = threadIdx.x;
    const int w = tid >> 6, l = tid & 63, fr = l & 15, fq = l >> 4;
    const int role = w >> 2, gate = w & 3;

    {   // stage both weight slices
        const f16* baseA = whh1 + ((size_t)branch << 18);
        const f16* baseB = wih1 + ((size_t)branch << 18);
        for (int c = tid; c < 8192; c += 512) {
            const int m2 = c >> 12;
            const int rl = (c & 4095) >> 6, coli = c & 63;
            const int gg = rl >> 4, f = (rl >> 3) & 1, ktp = rl & 7;
            const f16* src = (m2 ? baseB : baseA)
                + ((size_t)((gg * 16 + qm * 2 + f) * 8 + ktp) << 9) + coli * 8;
            *(uint4*)((m2 ? wldsB : wldsA) + rl * 512 + coli * 8) = *(const uint4*)src;
        }
    }
    ((uint4*)img)[tid] = (uint4){0u, 0u, 0u, 0u};   // 512 uint4 by 512 thr

    const float* bias = branch ? bR : bL;
    const int ubase = qm * 32 + (w < 2 ? w : 0) * 16 + fr;
    float bv[4];
#pragma unroll
    for (int g4 = 0; g4 < 4; ++g4) bv[g4] = bias[g4 * 256 + ubase];
    float cst[4] = {0.f, 0.f, 0.f, 0.f};
    const f16* gimg2 = h0img + (size_t)g * (NCLS * 4096);
    f16* gring = ring + (size_t)g * (4 * 4096);
    int* flgb = flags + g * 8 * 64;
    const f16* wmy = role ? wldsB : wldsA;

    f16x4 af[16];
    if (role) {                              // prefetch h0(0) frags
#pragma unroll
        for (int kt = 0; kt < 16; ++kt)
            af[kt] = *(const f16x4*)(gimg2 + kt * 256 + l * 4);
    }
    __syncthreads();

    for (int t = 0; t < NCLS; ++t) {
        if (!role) {
#pragma unroll
            for (int kt = 0; kt < 16; ++kt)
                af[kt] = *(const f16x4*)(img + kt * 256 + l * 4);
        }
        f32x4 acc[2];
#pragma unroll
        for (int f = 0; f < 2; ++f) {
            f32x4 a0 = {0.f,0.f,0.f,0.f}, a1 = {0.f,0.f,0.f,0.f};
#pragma unroll
            for (int ktp = 0; ktp < 8; ++ktp) {
                const f16x8 v = *(const f16x8*)(wmy + (((gate * 2 + f) * 8 + ktp) << 9) + l * 8);
                a0 = __builtin_amdgcn_mfma_f32_16x16x16f16(af[2 * ktp],     LO(v), a0, 0, 0, 0);
                a1 = __builtin_amdgcn_mfma_f32_16x16x16f16(af[2 * ktp + 1], HI(v), a1, 0, 0, 0);
            }
            acc[f] = a0 + a1;
        }
#pragma unroll
        for (int f = 0; f < 2; ++f)
#pragma unroll
            for (int r = 0; r < 4; ++r)
                cmb[((f * 4 + r) * 64 + l) * 9 + w] = acc[f][r];
        __syncthreads();                    // cmb ready; img af-reads done
        if (w < 2) {                        // finisher: frag f = w
            float hn[4];
#pragma unroll
            for (int r = 0; r < 4; ++r) {
                const int ci = ((w * 4 + r) * 64 + l) * 9;
                const float pi = cmb[ci + 0] + cmb[ci + 4] + bv[0];
                const float pf = cmb[ci + 1] + cmb[ci + 5] + bv[1];
                const float pg = cmb[ci + 2] + cmb[ci + 6] + bv[2];
                const float po = cmb[ci + 3] + cmb[ci + 7] + bv[3];
                const float ig = sigf(pi), fg = sigf(pf), gg = tanh_f(pg), og = sigf(po);
                cst[r] = fmaf(fg, cst[r], ig * gg);
                hn[r] = og * tanh_f(cst[r]);
            }
            if (t == NCLS - 1) {
#pragma unroll
                for (int r = 0; r < 4; ++r)
                    h1out[((size_t)(branch * NBATCH + tb * 16 + fq * 4 + r)) * NHID
                          + qm * 32 + w * 16 + fr] = hn[r];
            } else {
#pragma unroll
                for (int r = 0; r < 4; ++r)
                    img[(qm * 2 + w) * 256 + (fq * 4 + r + 16 * (fr >> 2)) * 4 + (fr & 3)] = (f16)hn[r];
            }
        }
        if (t == NCLS - 1) break;
        __syncthreads();                    // own 1 KB chunk complete in LDS
        f16* gdst = gring + (size_t)(t & 3) * 4096;
        if (w == 0) {
            ((uint2*)gdst)[qm * 128 + l]      = ((const uint2*)img)[qm * 128 + l];
            ((uint2*)gdst)[qm * 128 + 64 + l] = ((const uint2*)img)[qm * 128 + 64 + l];
            asm volatile("s_waitcnt vmcnt(0)" ::: "memory");
            if (l == 0)
                __hip_atomic_store(flgb + qm * 64, t + 1, __ATOMIC_RELEASE, __HIP_MEMORY_SCOPE_AGENT);
        }
        if (role) {                          // prefetch h0(t+1) frags (off critical path)
            const f16* s2 = gimg2 + (size_t)(t + 1) * 4096 + l * 4;
#pragma unroll
            for (int kt = 0; kt < 16; ++kt)
                af[kt] = *(const f16x4*)(s2 + kt * 256);
        }
        if (w == 0 && l < 7) {
            const int p = l + (l >= qm);
            while (__hip_atomic_load(flgb + p * 64, __ATOMIC_ACQUIRE, __HIP_MEMORY_SCOPE_AGENT) <= t)
                __builtin_amdgcn_s_sleep(1);
        }
        __syncthreads();                    // peers ready
        if (tid < 128) {
            uint2 tmp[7];
#pragma unroll
            for (int j = 0; j < 7; ++j) {
                const int p = j + (j >= qm);
                tmp[j] = ((const uint2*)gdst)[p * 128 + tid];
            }
#pragma unroll
            for (int j = 0; j < 7; ++j) {
                const int p = j + (j >= qm);
                ((uint2*)img)[p * 128 + tid] = tmp[j];
            }
        }
        __syncthreads();                    // img(t) complete
    }
}

// ---------------- K4: MLP head (2H -> 200 -> 128), f32 ------------------------
__global__ __launch_bounds__(256) void k_mlp(
    const float* __restrict__ h1all,   // [2][256][256]
    const float* __restrict__ W1, const float* __restrict__ b1,
    const float* __restrict__ W2, const float* __restrict__ b2,
    float* __restrict__ out)
{
    __shared__ float hrow[512];
    __shared__ float hid[200];
    const int b = blockIdx.x, tid = threadIdx.x;
    hrow[tid]       = h1all[(size_t)b * NHID + tid];
    hrow[256 + tid] = h1all[(size_t)(NBATCH + b) * NHID + tid];
    __syncthreads();
    if (tid < 200) {
        float a = b1[tid];
        const float* wr = W1 + (size_t)tid * 512;
        for (int k = 0; k < 512; ++k) a = fmaf(wr[k], hrow[k], a);
        hid[tid] = fmaxf(a, 0.f);
    }
    __syncthreads();
    if (tid < 128) {
        float a = b2[tid];
        const float* wr = W2 + (size_t)tid * 200;
        for (int j = 0; j < 200; ++j) a = fmaf(wr[j], hid[j], a);
        out[(size_t)b * 128 + tid] = a;
    }
}

// ---------------- launch ------------------------------------------------------
extern "C" void kernel_launch(void* const* d_in, const int* in_sizes, int n_in,
                              void* d_out, int out_size, void* d_ws, size_t ws_size,
                              hipStream_t stream)
{
    (void)in_sizes; (void)n_in; (void)out_size; (void)ws_size;
    const int*   ln    = (const int*)d_in[0];
    const int*   rn    = (const int*)d_in[2];
    const float* tlW   = (const float*)d_in[4];
    const float* tlU   = (const float*)d_in[5];
    const float* tlb   = (const float*)d_in[6];
    const float* trW   = (const float*)d_in[7];
    const float* trU   = (const float*)d_in[8];
    const float* trb   = (const float*)d_in[9];
    const float* wih0L = (const float*)d_in[10];
    const float* b0L   = (const float*)d_in[12];
    const float* b1L   = (const float*)d_in[15];
    const float* wih0R = (const float*)d_in[16];
    const float* b0R   = (const float*)d_in[18];
    const float* b1R   = (const float*)d_in[21];
    const float* mW1   = (const float*)d_in[22];
    const float* mb1   = (const float*)d_in[23];
    const float* mW2   = (const float*)d_in[24];
    const float* mb2   = (const float*)d_in[25];

    // workspace layout (bytes)
    char* ws = (char*)d_ws;
    f16*   w16    = (f16*)ws;                        // 3 MB swizzled weights
    float* states = (float*)(ws + 3145728);          // 256 KB
    float* h1out  = (float*)(ws + 3407872);          // 512 KB
    int*   flags  = (int*)(ws + 3932160);            // 128 KB (2 x 32 x 8 x 64 ints)
    f16*   h1ring = (f16*)(ws + 4063232);            // 1 MB
    f16*   h0img  = (f16*)(ws + 5111808);            // 32 MB

    f16* whh0 = w16;
    f16* whh1 = w16 + 2 * 262144;
    f16* wih1 = w16 + 4 * 262144;
    int* flags0 = flags;
    int* flags1 = flags + 16384;

    hipFuncSetAttribute(reinterpret_cast<const void*>(k_rec0),
                        hipFuncAttributeMaxDynamicSharedMemorySize, 92160);
    hipFuncSetAttribute(reinterpret_cast<const void*>(k_rec1),
                        hipFuncAttributeMaxDynamicSharedMemorySize, 157696);

    P6 p { (const float*)d_in[11], (const float*)d_in[17],   // nl_Whh0, nr_Whh0
           (const float*)d_in[14], (const float*)d_in[20],   // nl_Whh1, nr_Whh1
           (const float*)d_in[13], (const float*)d_in[19] }; // nl_Wih1, nr_Wih1
    k_zero<<<32, 1024, 0, stream>>>(flags);
    k_cvt<<<6144, 256, 0, stream>>>(p, w16);
    k_scalar_lstm<<<512, 128, 0, stream>>>(ln, rn, tlW, tlU, tlb, trW, trU, trb, states);
    k_rec0<<<256, 256, 92160, stream>>>(states, whh0, wih0L, wih0R, b0L, b0R, h0img, flags0);
    k_rec1<<<256, 512, 157696, stream>>>(whh1, wih1, h0img, b1L, b1R, h1ring, flags1, h1out);
    k_mlp<<<256, 256, 0, stream>>>(h1out, mW1, mb1, mW2, mb2, (float*)d_out);
}

// Round 8
// 1947.206 us; speedup vs baseline: 7.4006x; 1.0363x over previous
//
#include <hip/hip_runtime.h>

// VoiceModel: 2 branches x { scalar-LSTM(1->1,L2) over T=512 per (b,class),
// then LSTM(1->256,L2) over 128 class-steps }, concat -> MLP(512->200->128).
// Round 8 = round 7 with compile fix: LDS-resident weights, 8-way split,
// exchange DATA via relaxed agent-scope (sc1/LLC-coherent) 8B atomics.

typedef _Float16 f16;
typedef __attribute__((ext_vector_type(4))) _Float16 f16x4;
typedef __attribute__((ext_vector_type(8))) _Float16 f16x8;
typedef __attribute__((ext_vector_type(4))) float f32x4;
typedef unsigned long long u64;

#define NBATCH 256
#define NTIME  512
#define NCLS   128
#define NHID   256

__device__ __forceinline__ float sigf(float x) {
    return __builtin_amdgcn_rcpf(1.0f + __expf(-x));
}
__device__ __forceinline__ float tanh_f(float x) {
    return fmaf(2.0f, __builtin_amdgcn_rcpf(1.0f + __expf(-2.0f * x)), -1.0f);
}
__device__ __forceinline__ f16x4 LO(f16x8 v) { f16x4 r; r[0]=v[0]; r[1]=v[1]; r[2]=v[2]; r[3]=v[3]; return r; }
__device__ __forceinline__ f16x4 HI(f16x8 v) { f16x4 r; r[0]=v[4]; r[1]=v[5]; r[2]=v[6]; r[3]=v[7]; return r; }

// LLC-coherent (sc1) 8B data ops: relaxed agent atomics bypass L1/L2.
__device__ __forceinline__ u64 ld_llc(const u64* p) {
    return __hip_atomic_load(p, __ATOMIC_RELAXED, __HIP_MEMORY_SCOPE_AGENT);
}
__device__ __forceinline__ void st_llc(u64* p, u64 v) {
    __hip_atomic_store(p, v, __ATOMIC_RELAXED, __HIP_MEMORY_SCOPE_AGENT);
}

// ---------------- K0: convert + swizzle 6 weight matrices (1024x256) to f16 --
// layout per matrix: elem ((g*16+fi)*8+ktp)*512 + l*8 + e   (l = lane)
//   = W[g*256 + fi*16 + fr][ktp*32 + (e>>2)*16 + fq*4 + (e&3)]
struct P6 {
    const float* s0; const float* s1; const float* s2;
    const float* s3; const float* s4; const float* s5;
};

__global__ __launch_bounds__(256) void k_cvt(P6 p, f16* __restrict__ dst) {
    int i = blockIdx.x * 256 + threadIdx.x;      // 6 * 262144 total
    int seg = i >> 18, d = i & 262143;
    const float* s = seg == 0 ? p.s0 : seg == 1 ? p.s1 : seg == 2 ? p.s2
                   : seg == 3 ? p.s3 : seg == 4 ? p.s4 : p.s5;
    const int e  = d & 7;
    const int fr = (d >> 3) & 15;
    const int fq = (d >> 7) & 3;
    const int ktp = (d >> 9) & 7;
    const int fi = (d >> 12) & 15;
    const int g  = (d >> 16) & 3;
    const int row = g * 256 + fi * 16 + fr;
    const int col = ktp * 32 + (e >> 2) * 16 + fq * 4 + (e & 3);
    dst[i] = (f16)s[row * 256 + col];
}

// ---------------- zero the exchange flags (every call; graph-replay safe) ----
__global__ void k_zero(int* __restrict__ f) { f[blockIdx.x * 1024 + threadIdx.x] = 0; }

// ---------------- K1: scalar 2-layer LSTM per (branch, b, class) -------------
__global__ __launch_bounds__(128) void k_scalar_lstm(
    const int* __restrict__ ln, const int* __restrict__ rn,
    const float* __restrict__ tlW, const float* __restrict__ tlU, const float* __restrict__ tlb,
    const float* __restrict__ trW, const float* __restrict__ trU, const float* __restrict__ trb,
    float* __restrict__ states)
{
    __shared__ int tok[NTIME];
    const int bid = blockIdx.x;
    const int branch = bid >> 8;
    const int b = bid & 255;
    const int* tp = (branch ? rn : ln) + (size_t)b * (4 * NTIME);  // voice 0
    for (int i = threadIdx.x; i < NTIME; i += 128) tok[i] = tp[i];
    __syncthreads();
    const float* W  = branch ? trW : tlW;
    const float* U  = branch ? trU : tlU;
    const float* Bb = branch ? trb : tlb;
    const float u00 = U[0], u01 = U[1], u02 = U[2], u03 = U[3];
    const float f00 = Bb[0], f01 = Bb[1], f02 = Bb[2], f03 = Bb[3];
    const float o00 = f00 + W[0], o01 = f01 + W[1], o02 = f02 + W[2], o03 = f03 + W[3];
    const float w10 = W[4], w11 = W[5], w12 = W[6], w13 = W[7];
    const float u10 = U[4], u11 = U[5], u12 = U[6], u13 = U[7];
    const float b10 = Bb[4], b11 = Bb[5], b12 = Bb[6], b13 = Bb[7];
    const int n = threadIdx.x;
    float h0 = 0.f, c0 = 0.f, h1 = 0.f, c1 = 0.f;
    for (int t = 0; t < NTIME; ++t) {
        const bool x = (tok[t] == n);
        float pi = fmaf(u00, h0, x ? o00 : f00);
        float pf = fmaf(u01, h0, x ? o01 : f01);
        float pg = fmaf(u02, h0, x ? o02 : f02);
        float po = fmaf(u03, h0, x ? o03 : f03);
        float ig = sigf(pi), fg = sigf(pf), gg = tanh_f(pg), og = sigf(po);
        c0 = fmaf(fg, c0, ig * gg);
        h0 = og * tanh_f(c0);
        pi = fmaf(w10, h0, fmaf(u10, h1, b10));
        pf = fmaf(w11, h0, fmaf(u11, h1, b11));
        pg = fmaf(w12, h0, fmaf(u12, h1, b12));
        po = fmaf(w13, h0, fmaf(u13, h1, b13));
        ig = sigf(pi); fg = sigf(pf); gg = tanh_f(pg); og = sigf(po);
        c1 = fmaf(fg, c1, ig * gg);
        h1 = og * tanh_f(c1);
    }
    states[((size_t)(branch * NBATCH + b)) * NCLS + n] = h1;
}

// ---------------- K2: layer-0 recurrence, 8-way split, LDS weights -----------
// grid 256: blockIdx = group(32) + 32*member(8).
// Block owns hidden units [qm*32, qm*32+32), all 4 gates (128 rows): 64 KB LDS.
// 4 waves = 4 gates; waves 0,1 finish frags 0,1. Exchange payload via sc1
// relaxed atomics (LLC-coherent); flags acquire/release agent (padded 256 B).
__global__ __launch_bounds__(256, 1) void k_rec0(
    const float* __restrict__ states,
    const f16* __restrict__ whh0,
    const float* __restrict__ wih0L, const float* __restrict__ wih0R,
    const float* __restrict__ bL, const float* __restrict__ bR,
    f16* __restrict__ h0img,               // [32 group][128 t][4096]
    int* __restrict__ flags)               // [32 group][8 member] stride 64 ints
{
    extern __shared__ char smem[];
    f16*   wlds = (f16*)smem;                    // 65536 B
    f16*   img  = (f16*)(smem + 65536);          // 8192 B
    float* lst  = (float*)(smem + 73728);        // 8192 B
    float* cmb  = (float*)(smem + 81920);        // 10240 B (stride-5 floats)

    const int qm = blockIdx.x >> 5, g = blockIdx.x & 31;
    const int branch = g >> 4, tb = g & 15;
    const int tid = threadIdx.x;
    const int w = tid >> 6, l = tid & 63, fr = l & 15, fq = l >> 4;

    {   // stage Whh0 slice: 64 rows (g2*2+f)*8+ktp of 512 f16
        const f16* base = whh0 + ((size_t)branch << 18);
        for (int c = tid; c < 4096; c += 256) {
            const int rl = c >> 6, coli = c & 63;
            const int gg = rl >> 4, f = (rl >> 3) & 1, ktp = rl & 7;
            *(uint4*)(wlds + rl * 512 + coli * 8) =
                *(const uint4*)(base + ((size_t)((gg * 16 + qm * 2 + f) * 8 + ktp) << 9) + coli * 8);
        }
    }
    for (int i = tid; i < 16 * NCLS; i += 256)
        lst[i] = states[((size_t)(branch * NBATCH + tb * 16 + (i >> 7))) * NCLS + (i & 127)];
    ((uint4*)img)[tid] = (uint4){0u, 0u, 0u, 0u};
    ((uint4*)img)[tid + 256] = (uint4){0u, 0u, 0u, 0u};

    const float* bias = branch ? bR : bL;
    const float* w0p  = branch ? wih0R : wih0L;
    const int ubase = qm * 32 + (w < 2 ? w : 0) * 16 + fr;
    float bv[4], w0v[4];
#pragma unroll
    for (int g4 = 0; g4 < 4; ++g4) {
        bv[g4]  = bias[g4 * 256 + ubase];
        w0v[g4] = w0p[g4 * 256 + ubase];
    }
    float cst[4] = {0.f, 0.f, 0.f, 0.f};
    f16* gimg = h0img + (size_t)g * (NCLS * 4096);
    int* flgb = flags + g * 8 * 64;
    __syncthreads();

    for (int t = 0; t < NCLS; ++t) {
        f16x4 af[16];
#pragma unroll
        for (int kt = 0; kt < 16; ++kt)
            af[kt] = *(const f16x4*)(img + kt * 256 + l * 4);
        f32x4 acc[2];
#pragma unroll
        for (int f = 0; f < 2; ++f) {
            f32x4 a0 = {0.f,0.f,0.f,0.f}, a1 = {0.f,0.f,0.f,0.f};
#pragma unroll
            for (int ktp = 0; ktp < 8; ++ktp) {
                const f16x8 v = *(const f16x8*)(wlds + (((w * 2 + f) * 8 + ktp) << 9) + l * 8);
                a0 = __builtin_amdgcn_mfma_f32_16x16x16f16(af[2 * ktp],     LO(v), a0, 0, 0, 0);
                a1 = __builtin_amdgcn_mfma_f32_16x16x16f16(af[2 * ktp + 1], HI(v), a1, 0, 0, 0);
            }
            acc[f] = a0 + a1;
        }
#pragma unroll
        for (int f = 0; f < 2; ++f)
#pragma unroll
            for (int r = 0; r < 4; ++r)
                cmb[((f * 4 + r) * 64 + l) * 5 + w] = acc[f][r];
        __syncthreads();                    // cmb ready; img af-reads done
        if (w < 2) {                        // finisher: frag f = w
#pragma unroll
            for (int r = 0; r < 4; ++r) {
                const int ci = ((w * 4 + r) * 64 + l) * 5;
                const float st = lst[(fq * 4 + r) * NCLS + t];
                const float pi = fmaf(st, w0v[0], cmb[ci + 0] + bv[0]);
                const float pf = fmaf(st, w0v[1], cmb[ci + 1] + bv[1]);
                const float pg = fmaf(st, w0v[2], cmb[ci + 2] + bv[2]);
                const float po = fmaf(st, w0v[3], cmb[ci + 3] + bv[3]);
                const float ig = sigf(pi), fg = sigf(pf), gg = tanh_f(pg), og = sigf(po);
                cst[r] = fmaf(fg, cst[r], ig * gg);
                const float hn = og * tanh_f(cst[r]);
                img[(qm * 2 + w) * 256 + (fq * 4 + r + 16 * (fr >> 2)) * 4 + (fr & 3)] = (f16)hn;
            }
        }
        __syncthreads();                    // own 1 KB chunk complete in LDS
        if (w == 0) {                       // wave 0 pushes chunk via sc1/LLC
            u64* gd = (u64*)(gimg + (size_t)t * 4096);
            st_llc(gd + qm * 128 + l,      ((const u64*)img)[qm * 128 + l]);
            st_llc(gd + qm * 128 + 64 + l, ((const u64*)img)[qm * 128 + 64 + l]);
        }
        if (t == NCLS - 1) break;
        if (w == 0) {
            asm volatile("s_waitcnt vmcnt(0)" ::: "memory");
            if (l == 0)
                __hip_atomic_store(flgb + qm * 64, t + 1, __ATOMIC_RELEASE, __HIP_MEMORY_SCOPE_AGENT);
            if (l < 7) {
                const int p = l + (l >= qm);
                while (__hip_atomic_load(flgb + p * 64, __ATOMIC_ACQUIRE, __HIP_MEMORY_SCOPE_AGENT) <= t)
                    __builtin_amdgcn_s_sleep(1);
            }
        }
        __syncthreads();                    // peers ready
        if (tid < 128) {                    // gather 7 KB from LLC
            const u64* gs = (const u64*)(gimg + (size_t)t * 4096);
            u64 tmp[7];
#pragma unroll
            for (int j = 0; j < 7; ++j) {
                const int p = j + (j >= qm);
                tmp[j] = ld_llc(gs + p * 128 + tid);
            }
#pragma unroll
            for (int j = 0; j < 7; ++j) {
                const int p = j + (j >= qm);
                ((u64*)img)[p * 128 + tid] = tmp[j];
            }
        }
        __syncthreads();                    // img(t) complete
    }
}

// ---------------- K3: layer-1 recurrence, 8-way split, both weights in LDS ----
// grid 256 (same mapping), 512 thr = 8 waves: role = w>>2 (0 rec / 1 input),
// gate = w&3. Input waves register-prefetch h0(t+1) frags via sc1 loads.
__global__ __launch_bounds__(512, 1) void k_rec1(
    const f16* __restrict__ whh1,
    const f16* __restrict__ wih1,
    const f16* __restrict__ h0img,         // [32][128][4096]
    const float* __restrict__ bL, const float* __restrict__ bR,
    f16* __restrict__ ring,                // [32 group][4 slot][4096]
    int* __restrict__ flags,               // [32 group][8] stride 64 ints
    float* __restrict__ h1out)             // [2][256][256] f32
{
    extern __shared__ char smem[];
    f16*   wldsA = (f16*)smem;                   // 65536 B (Whh1)
    f16*   wldsB = (f16*)(smem + 65536);         // 65536 B (Wih1)
    f16*   img   = (f16*)(smem + 131072);        // 8192 B
    float* cmb   = (float*)(smem + 139264);      // 18432 B (stride-9 floats)

    const int qm = blockIdx.x >> 5, g = blockIdx.x & 31;
    const int branch = g >> 4, tb = g & 15;
    const int tid = threadIdx.x;
    const int w = tid >> 6, l = tid & 63, fr = l & 15, fq = l >> 4;
    const int role = w >> 2, gate = w & 3;

    {   // stage both weight slices
        const f16* baseA = whh1 + ((size_t)branch << 18);
        const f16* baseB = wih1 + ((size_t)branch << 18);
        for (int c = tid; c < 8192; c += 512) {
            const int m2 = c >> 12;
            const int rl = (c & 4095) >> 6, coli = c & 63;
            const int gg = rl >> 4, f = (rl >> 3) & 1, ktp = rl & 7;
            const f16* src = (m2 ? baseB : baseA)
                + ((size_t)((gg * 16 + qm * 2 + f) * 8 + ktp) << 9) + coli * 8;
            *(uint4*)((m2 ? wldsB : wldsA) + rl * 512 + coli * 8) = *(const uint4*)src;
        }
    }
    ((uint4*)img)[tid] = (uint4){0u, 0u, 0u, 0u};   // 512 uint4 by 512 thr

    const float* bias = branch ? bR : bL;
    const int ubase = qm * 32 + (w < 2 ? w : 0) * 16 + fr;
    float bv[4];
#pragma unroll
    for (int g4 = 0; g4 < 4; ++g4) bv[g4] = bias[g4 * 256 + ubase];
    float cst[4] = {0.f, 0.f, 0.f, 0.f};
    const f16* gimg2 = h0img + (size_t)g * (NCLS * 4096);
    f16* gring = ring + (size_t)g * (4 * 4096);
    int* flgb = flags + g * 8 * 64;
    const f16* wmy = role ? wldsB : wldsA;

    f16x4 af[16];
    if (role) {                              // prefetch h0(0) frags via LLC
        const u64* s2 = (const u64*)gimg2 + l;
#pragma unroll
        for (int kt = 0; kt < 16; ++kt)
            af[kt] = __builtin_bit_cast(f16x4, ld_llc(s2 + kt * 64));
    }
    __syncthreads();

    for (int t = 0; t < NCLS; ++t) {
        if (!role) {
#pragma unroll
            for (int kt = 0; kt < 16; ++kt)
                af[kt] = *(const f16x4*)(img + kt * 256 + l * 4);
        }
        f32x4 acc[2];
#pragma unroll
        for (int f = 0; f < 2; ++f) {
            f32x4 a0 = {0.f,0.f,0.f,0.f}, a1 = {0.f,0.f,0.f,0.f};
#pragma unroll
            for (int ktp = 0; ktp < 8; ++ktp) {
                const f16x8 v = *(const f16x8*)(wmy + (((gate * 2 + f) * 8 + ktp) << 9) + l * 8);
                a0 = __builtin_amdgcn_mfma_f32_16x16x16f16(af[2 * ktp],     LO(v), a0, 0, 0, 0);
                a1 = __builtin_amdgcn_mfma_f32_16x16x16f16(af[2 * ktp + 1], HI(v), a1, 0, 0, 0);
            }
            acc[f] = a0 + a1;
        }
#pragma unroll
        for (int f = 0; f < 2; ++f)
#pragma unroll
            for (int r = 0; r < 4; ++r)
                cmb[((f * 4 + r) * 64 + l) * 9 + w] = acc[f][r];
        __syncthreads();                    // cmb ready; img af-reads done
        if (w < 2) {                        // finisher: frag f = w
            float hn[4];
#pragma unroll
            for (int r = 0; r < 4; ++r) {
                const int ci = ((w * 4 + r) * 64 + l) * 9;
                const float pi = cmb[ci + 0] + cmb[ci + 4] + bv[0];
                const float pf = cmb[ci + 1] + cmb[ci + 5] + bv[1];
                const float pg = cmb[ci + 2] + cmb[ci + 6] + bv[2];
                const float po = cmb[ci + 3] + cmb[ci + 7] + bv[3];
                const float ig = sigf(pi), fg = sigf(pf), gg = tanh_f(pg), og = sigf(po);
                cst[r] = fmaf(fg, cst[r], ig * gg);
                hn[r] = og * tanh_f(cst[r]);
            }
            if (t == NCLS - 1) {
#pragma unroll
                for (int r = 0; r < 4; ++r)
                    h1out[((size_t)(branch * NBATCH + tb * 16 + fq * 4 + r)) * NHID
                          + qm * 32 + w * 16 + fr] = hn[r];
            } else {
#pragma unroll
                for (int r = 0; r < 4; ++r)
                    img[(qm * 2 + w) * 256 + (fq * 4 + r + 16 * (fr >> 2)) * 4 + (fr & 3)] = (f16)hn[r];
            }
        }
        if (t == NCLS - 1) break;
        __syncthreads();                    // own 1 KB chunk complete in LDS
        f16* gdst = gring + (size_t)(t & 3) * 4096;
        if (w == 0) {                       // push chunk via sc1/LLC
            u64* gd = (u64*)gdst;
            st_llc(gd + qm * 128 + l,      ((const u64*)img)[qm * 128 + l]);
            st_llc(gd + qm * 128 + 64 + l, ((const u64*)img)[qm * 128 + 64 + l]);
            asm volatile("s_waitcnt vmcnt(0)" ::: "memory");
            if (l == 0)
                __hip_atomic_store(flgb + qm * 64, t + 1, __ATOMIC_RELEASE, __HIP_MEMORY_SCOPE_AGENT);
        }
        if (role) {                          // prefetch h0(t+1) frags via LLC
            const u64* s2 = (const u64*)(gimg2 + (size_t)(t + 1) * 4096) + l;
#pragma unroll
            for (int kt = 0; kt < 16; ++kt)
                af[kt] = __builtin_bit_cast(f16x4, ld_llc(s2 + kt * 64));
        }
        if (w == 0 && l < 7) {
            const int p = l + (l >= qm);
            while (__hip_atomic_load(flgb + p * 64, __ATOMIC_ACQUIRE, __HIP_MEMORY_SCOPE_AGENT) <= t)
                __builtin_amdgcn_s_sleep(1);
        }
        __syncthreads();                    // peers ready
        if (tid < 128) {                    // gather 7 KB from LLC
            u64 tmp[7];
            const u64* gs = (const u64*)gdst;
#pragma unroll
            for (int j = 0; j < 7; ++j) {
                const int p = j + (j >= qm);
                tmp[j] = ld_llc(gs + p * 128 + tid);
            }
#pragma unroll
            for (int j = 0; j < 7; ++j) {
                const int p = j + (j >= qm);
                ((u64*)img)[p * 128 + tid] = tmp[j];
            }
        }
        __syncthreads();                    // img(t) complete
    }
}

// ---------------- K4: MLP head (2H -> 200 -> 128), f32 ------------------------
__global__ __launch_bounds__(256) void k_mlp(
    const float* __restrict__ h1all,   // [2][256][256]
    const float* __restrict__ W1, const float* __restrict__ b1,
    const float* __restrict__ W2, const float* __restrict__ b2,
    float* __restrict__ out)
{
    __shared__ float hrow[512];
    __shared__ float hid[200];
    const int b = blockIdx.x, tid = threadIdx.x;
    hrow[tid]       = h1all[(size_t)b * NHID + tid];
    hrow[256 + tid] = h1all[(size_t)(NBATCH + b) * NHID + tid];
    __syncthreads();
    if (tid < 200) {
        float a = b1[tid];
        const float* wr = W1 + (size_t)tid * 512;
        for (int k = 0; k < 512; ++k) a = fmaf(wr[k], hrow[k], a);
        hid[tid] = fmaxf(a, 0.f);
    }
    __syncthreads();
    if (tid < 128) {
        float a = b2[tid];
        const float* wr = W2 + (size_t)tid * 200;
        for (int j = 0; j < 200; ++j) a = fmaf(wr[j], hid[j], a);
        out[(size_t)b * 128 + tid] = a;
    }
}

// ---------------- launch ------------------------------------------------------
extern "C" void kernel_launch(void* const* d_in, const int* in_sizes, int n_in,
                              void* d_out, int out_size, void* d_ws, size_t ws_size,
                              hipStream_t stream)
{
    (void)in_sizes; (void)n_in; (void)out_size; (void)ws_size;
    const int*   ln    = (const int*)d_in[0];
    const int*   rn    = (const int*)d_in[2];
    const float* tlW   = (const float*)d_in[4];
    const float* tlU   = (const float*)d_in[5];
    const float* tlb   = (const float*)d_in[6];
    const float* trW   = (const float*)d_in[7];
    const float* trU   = (const float*)d_in[8];
    const float* trb   = (const float*)d_in[9];
    const float* wih0L = (const float*)d_in[10];
    const float* b0L   = (const float*)d_in[12];
    const float* b1L   = (const float*)d_in[15];
    const float* wih0R = (const float*)d_in[16];
    const float* b0R   = (const float*)d_in[18];
    const float* b1R   = (const float*)d_in[21];
    const float* mW1   = (const float*)d_in[22];
    const float* mb1   = (const float*)d_in[23];
    const float* mW2   = (const float*)d_in[24];
    const float* mb2   = (const float*)d_in[25];

    // workspace layout (bytes)
    char* ws = (char*)d_ws;
    f16*   w16    = (f16*)ws;                        // 3 MB swizzled weights
    float* states = (float*)(ws + 3145728);          // 256 KB
    float* h1out  = (float*)(ws + 3407872);          // 512 KB
    int*   flags  = (int*)(ws + 3932160);            // 128 KB (2 x 32 x 8 x 64 ints)
    f16*   h1ring = (f16*)(ws + 4063232);            // 1 MB
    f16*   h0img  = (f16*)(ws + 5111808);            // 32 MB

    f16* whh0 = w16;
    f16* whh1 = w16 + 2 * 262144;
    f16* wih1 = w16 + 4 * 262144;
    int* flags0 = flags;
    int* flags1 = flags + 16384;

    (void)hipFuncSetAttribute(reinterpret_cast<const void*>(k_rec0),
                              hipFuncAttributeMaxDynamicSharedMemorySize, 92160);
    (void)hipFuncSetAttribute(reinterpret_cast<const void*>(k_rec1),
                              hipFuncAttributeMaxDynamicSharedMemorySize, 157696);

    P6 p { (const float*)d_in[11], (const float*)d_in[17],   // nl_Whh0, nr_Whh0
           (const float*)d_in[14], (const float*)d_in[20],   // nl_Whh1, nr_Whh1
           (const float*)d_in[13], (const float*)d_in[19] }; // nl_Wih1, nr_Wih1
    k_zero<<<32, 1024, 0, stream>>>(flags);
    k_cvt<<<6144, 256, 0, stream>>>(p, w16);
    k_scalar_lstm<<<512, 128, 0, stream>>>(ln, rn, tlW, tlU, tlb, trW, trU, trb, states);
    k_rec0<<<256, 256, 92160, stream>>>(states, whh0, wih0L, wih0R, b0L, b0R, h0img, flags0);
    k_rec1<<<256, 512, 157696, stream>>>(whh1, wih1, h0img, b1L, b1R, h1ring, flags1, h1out);
    k_mlp<<<256, 256, 0, stream>>>(h1out, mW1, mb1, mW2, mb2, (float*)d_out);
}

// Round 9
// 894.541 us; speedup vs baseline: 16.1095x; 2.1768x over previous
//
#include <hip/hip_runtime.h>

// VoiceModel: 2 branches x { scalar-LSTM(1->1,L2) over T=512 per (b,class),
// then LSTM(1->256,L2) over 128 class-steps }, concat -> MLP(512->200->128).
// Round 9 = round 8 with flags RELAXED (no agent acquire/release -> no per-step
// L2 writeback/invalidate). Ordering via explicit vmcnt(0) + sc1 LLC path.

typedef _Float16 f16;
typedef __attribute__((ext_vector_type(4))) _Float16 f16x4;
typedef __attribute__((ext_vector_type(8))) _Float16 f16x8;
typedef __attribute__((ext_vector_type(4))) float f32x4;
typedef unsigned long long u64;

#define NBATCH 256
#define NTIME  512
#define NCLS   128
#define NHID   256

__device__ __forceinline__ float sigf(float x) {
    return __builtin_amdgcn_rcpf(1.0f + __expf(-x));
}
__device__ __forceinline__ float tanh_f(float x) {
    return fmaf(2.0f, __builtin_amdgcn_rcpf(1.0f + __expf(-2.0f * x)), -1.0f);
}
__device__ __forceinline__ f16x4 LO(f16x8 v) { f16x4 r; r[0]=v[0]; r[1]=v[1]; r[2]=v[2]; r[3]=v[3]; return r; }
__device__ __forceinline__ f16x4 HI(f16x8 v) { f16x4 r; r[0]=v[4]; r[1]=v[5]; r[2]=v[6]; r[3]=v[7]; return r; }

// LLC-coherent (sc1) 8B data ops: relaxed agent atomics bypass L1/L2, no
// cache-maintenance instructions emitted.
__device__ __forceinline__ u64 ld_llc(const u64* p) {
    return __hip_atomic_load(p, __ATOMIC_RELAXED, __HIP_MEMORY_SCOPE_AGENT);
}
__device__ __forceinline__ void st_llc(u64* p, u64 v) {
    __hip_atomic_store(p, v, __ATOMIC_RELAXED, __HIP_MEMORY_SCOPE_AGENT);
}

// ---------------- K0: convert + swizzle 6 weight matrices (1024x256) to f16 --
// layout per matrix: elem ((g*16+fi)*8+ktp)*512 + l*8 + e   (l = lane)
//   = W[g*256 + fi*16 + fr][ktp*32 + (e>>2)*16 + fq*4 + (e&3)]
struct P6 {
    const float* s0; const float* s1; const float* s2;
    const float* s3; const float* s4; const float* s5;
};

__global__ __launch_bounds__(256) void k_cvt(P6 p, f16* __restrict__ dst) {
    int i = blockIdx.x * 256 + threadIdx.x;      // 6 * 262144 total
    int seg = i >> 18, d = i & 262143;
    const float* s = seg == 0 ? p.s0 : seg == 1 ? p.s1 : seg == 2 ? p.s2
                   : seg == 3 ? p.s3 : seg == 4 ? p.s4 : p.s5;
    const int e  = d & 7;
    const int fr = (d >> 3) & 15;
    const int fq = (d >> 7) & 3;
    const int ktp = (d >> 9) & 7;
    const int fi = (d >> 12) & 15;
    const int g  = (d >> 16) & 3;
    const int row = g * 256 + fi * 16 + fr;
    const int col = ktp * 32 + (e >> 2) * 16 + fq * 4 + (e & 3);
    dst[i] = (f16)s[row * 256 + col];
}

// ---------------- zero the exchange flags (every call; graph-replay safe) ----
__global__ void k_zero(int* __restrict__ f) { f[blockIdx.x * 1024 + threadIdx.x] = 0; }

// ---------------- K1: scalar 2-layer LSTM per (branch, b, class) -------------
__global__ __launch_bounds__(128) void k_scalar_lstm(
    const int* __restrict__ ln, const int* __restrict__ rn,
    const float* __restrict__ tlW, const float* __restrict__ tlU, const float* __restrict__ tlb,
    const float* __restrict__ trW, const float* __restrict__ trU, const float* __restrict__ trb,
    float* __restrict__ states)
{
    __shared__ int tok[NTIME];
    const int bid = blockIdx.x;
    const int branch = bid >> 8;
    const int b = bid & 255;
    const int* tp = (branch ? rn : ln) + (size_t)b * (4 * NTIME);  // voice 0
    for (int i = threadIdx.x; i < NTIME; i += 128) tok[i] = tp[i];
    __syncthreads();
    const float* W  = branch ? trW : tlW;
    const float* U  = branch ? trU : tlU;
    const float* Bb = branch ? trb : tlb;
    const float u00 = U[0], u01 = U[1], u02 = U[2], u03 = U[3];
    const float f00 = Bb[0], f01 = Bb[1], f02 = Bb[2], f03 = Bb[3];
    const float o00 = f00 + W[0], o01 = f01 + W[1], o02 = f02 + W[2], o03 = f03 + W[3];
    const float w10 = W[4], w11 = W[5], w12 = W[6], w13 = W[7];
    const float u10 = U[4], u11 = U[5], u12 = U[6], u13 = U[7];
    const float b10 = Bb[4], b11 = Bb[5], b12 = Bb[6], b13 = Bb[7];
    const int n = threadIdx.x;
    float h0 = 0.f, c0 = 0.f, h1 = 0.f, c1 = 0.f;
    for (int t = 0; t < NTIME; ++t) {
        const bool x = (tok[t] == n);
        float pi = fmaf(u00, h0, x ? o00 : f00);
        float pf = fmaf(u01, h0, x ? o01 : f01);
        float pg = fmaf(u02, h0, x ? o02 : f02);
        float po = fmaf(u03, h0, x ? o03 : f03);
        float ig = sigf(pi), fg = sigf(pf), gg = tanh_f(pg), og = sigf(po);
        c0 = fmaf(fg, c0, ig * gg);
        h0 = og * tanh_f(c0);
        pi = fmaf(w10, h0, fmaf(u10, h1, b10));
        pf = fmaf(w11, h0, fmaf(u11, h1, b11));
        pg = fmaf(w12, h0, fmaf(u12, h1, b12));
        po = fmaf(w13, h0, fmaf(u13, h1, b13));
        ig = sigf(pi); fg = sigf(pf); gg = tanh_f(pg); og = sigf(po);
        c1 = fmaf(fg, c1, ig * gg);
        h1 = og * tanh_f(c1);
    }
    states[((size_t)(branch * NBATCH + b)) * NCLS + n] = h1;
}

// ---------------- K2: layer-0 recurrence, 8-way split, LDS weights -----------
// grid 256: blockIdx = group(32) + 32*member(8).
// Block owns hidden units [qm*32, qm*32+32), all 4 gates (128 rows): 64 KB LDS.
// 4 waves = 4 gates; waves 0,1 finish frags 0,1. All exchange ops relaxed sc1;
// write-ordering by explicit vmcnt(0) before the flag store.
__global__ __launch_bounds__(256, 1) void k_rec0(
    const float* __restrict__ states,
    const f16* __restrict__ whh0,
    const float* __restrict__ wih0L, const float* __restrict__ wih0R,
    const float* __restrict__ bL, const float* __restrict__ bR,
    f16* __restrict__ h0img,               // [32 group][128 t][4096]
    int* __restrict__ flags)               // [32 group][8 member] stride 64 ints
{
    extern __shared__ char smem[];
    f16*   wlds = (f16*)smem;                    // 65536 B
    f16*   img  = (f16*)(smem + 65536);          // 8192 B
    float* lst  = (float*)(smem + 73728);        // 8192 B
    float* cmb  = (float*)(smem + 81920);        // 10240 B (stride-5 floats)

    const int qm = blockIdx.x >> 5, g = blockIdx.x & 31;
    const int branch = g >> 4, tb = g & 15;
    const int tid = threadIdx.x;
    const int w = tid >> 6, l = tid & 63, fr = l & 15, fq = l >> 4;

    {   // stage Whh0 slice: 64 rows (g2*2+f)*8+ktp of 512 f16
        const f16* base = whh0 + ((size_t)branch << 18);
        for (int c = tid; c < 4096; c += 256) {
            const int rl = c >> 6, coli = c & 63;
            const int gg = rl >> 4, f = (rl >> 3) & 1, ktp = rl & 7;
            *(uint4*)(wlds + rl * 512 + coli * 8) =
                *(const uint4*)(base + ((size_t)((gg * 16 + qm * 2 + f) * 8 + ktp) << 9) + coli * 8);
        }
    }
    for (int i = tid; i < 16 * NCLS; i += 256)
        lst[i] = states[((size_t)(branch * NBATCH + tb * 16 + (i >> 7))) * NCLS + (i & 127)];
    ((uint4*)img)[tid] = (uint4){0u, 0u, 0u, 0u};
    ((uint4*)img)[tid + 256] = (uint4){0u, 0u, 0u, 0u};

    const float* bias = branch ? bR : bL;
    const float* w0p  = branch ? wih0R : wih0L;
    const int ubase = qm * 32 + (w < 2 ? w : 0) * 16 + fr;
    float bv[4], w0v[4];
#pragma unroll
    for (int g4 = 0; g4 < 4; ++g4) {
        bv[g4]  = bias[g4 * 256 + ubase];
        w0v[g4] = w0p[g4 * 256 + ubase];
    }
    float cst[4] = {0.f, 0.f, 0.f, 0.f};
    f16* gimg = h0img + (size_t)g * (NCLS * 4096);
    int* flgb = flags + g * 8 * 64;
    __syncthreads();

    for (int t = 0; t < NCLS; ++t) {
        f16x4 af[16];
#pragma unroll
        for (int kt = 0; kt < 16; ++kt)
            af[kt] = *(const f16x4*)(img + kt * 256 + l * 4);
        f32x4 acc[2];
#pragma unroll
        for (int f = 0; f < 2; ++f) {
            f32x4 a0 = {0.f,0.f,0.f,0.f}, a1 = {0.f,0.f,0.f,0.f};
#pragma unroll
            for (int ktp = 0; ktp < 8; ++ktp) {
                const f16x8 v = *(const f16x8*)(wlds + (((w * 2 + f) * 8 + ktp) << 9) + l * 8);
                a0 = __builtin_amdgcn_mfma_f32_16x16x16f16(af[2 * ktp],     LO(v), a0, 0, 0, 0);
                a1 = __builtin_amdgcn_mfma_f32_16x16x16f16(af[2 * ktp + 1], HI(v), a1, 0, 0, 0);
            }
            acc[f] = a0 + a1;
        }
#pragma unroll
        for (int f = 0; f < 2; ++f)
#pragma unroll
            for (int r = 0; r < 4; ++r)
                cmb[((f * 4 + r) * 64 + l) * 5 + w] = acc[f][r];
        __syncthreads();                    // cmb ready; img af-reads done
        if (w < 2) {                        // finisher: frag f = w
#pragma unroll
            for (int r = 0; r < 4; ++r) {
                const int ci = ((w * 4 + r) * 64 + l) * 5;
                const float st = lst[(fq * 4 + r) * NCLS + t];
                const float pi = fmaf(st, w0v[0], cmb[ci + 0] + bv[0]);
                const float pf = fmaf(st, w0v[1], cmb[ci + 1] + bv[1]);
                const float pg = fmaf(st, w0v[2], cmb[ci + 2] + bv[2]);
                const float po = fmaf(st, w0v[3], cmb[ci + 3] + bv[3]);
                const float ig = sigf(pi), fg = sigf(pf), gg = tanh_f(pg), og = sigf(po);
                cst[r] = fmaf(fg, cst[r], ig * gg);
                const float hn = og * tanh_f(cst[r]);
                img[(qm * 2 + w) * 256 + (fq * 4 + r + 16 * (fr >> 2)) * 4 + (fr & 3)] = (f16)hn;
            }
        }
        __syncthreads();                    // own 1 KB chunk complete in LDS
        if (w == 0) {                       // wave 0 pushes chunk via sc1/LLC
            u64* gd = (u64*)(gimg + (size_t)t * 4096);
            st_llc(gd + qm * 128 + l,      ((const u64*)img)[qm * 128 + l]);
            st_llc(gd + qm * 128 + 64 + l, ((const u64*)img)[qm * 128 + 64 + l]);
        }
        if (t == NCLS - 1) break;
        if (w == 0) {
            asm volatile("s_waitcnt vmcnt(0)" ::: "memory");   // chunk at LLC
            if (l == 0)
                __hip_atomic_store(flgb + qm * 64, t + 1, __ATOMIC_RELAXED, __HIP_MEMORY_SCOPE_AGENT);
            if (l < 7) {
                const int p = l + (l >= qm);
                while (__hip_atomic_load(flgb + p * 64, __ATOMIC_RELAXED, __HIP_MEMORY_SCOPE_AGENT) <= t)
                    __builtin_amdgcn_s_sleep(1);
            }
        }
        __syncthreads();                    // peers ready
        if (tid < 128) {                    // gather 7 KB from LLC
            const u64* gs = (const u64*)(gimg + (size_t)t * 4096);
            u64 tmp[7];
#pragma unroll
            for (int j = 0; j < 7; ++j) {
                const int p = j + (j >= qm);
                tmp[j] = ld_llc(gs + p * 128 + tid);
            }
#pragma unroll
            for (int j = 0; j < 7; ++j) {
                const int p = j + (j >= qm);
                ((u64*)img)[p * 128 + tid] = tmp[j];
            }
        }
        __syncthreads();                    // img(t) complete
    }
}

// ---------------- K3: layer-1 recurrence, 8-way split, both weights in LDS ----
// grid 256 (same mapping), 512 thr = 8 waves: role = w>>2 (0 rec / 1 input),
// gate = w&3. Input waves register-prefetch h0(t+1) frags via sc1 loads.
__global__ __launch_bounds__(512, 1) void k_rec1(
    const f16* __restrict__ whh1,
    const f16* __restrict__ wih1,
    const f16* __restrict__ h0img,         // [32][128][4096]
    const float* __restrict__ bL, const float* __restrict__ bR,
    f16* __restrict__ ring,                // [32 group][4 slot][4096]
    int* __restrict__ flags,               // [32 group][8] stride 64 ints
    float* __restrict__ h1out)             // [2][256][256] f32
{
    extern __shared__ char smem[];
    f16*   wldsA = (f16*)smem;                   // 65536 B (Whh1)
    f16*   wldsB = (f16*)(smem + 65536);         // 65536 B (Wih1)
    f16*   img   = (f16*)(smem + 131072);        // 8192 B
    float* cmb   = (float*)(smem + 139264);      // 18432 B (stride-9 floats)

    const int qm = blockIdx.x >> 5, g = blockIdx.x & 31;
    const int branch = g >> 4, tb = g & 15;
    const int tid = threadIdx.x;
    const int w = tid >> 6, l = tid & 63, fr = l & 15, fq = l >> 4;
    const int role = w >> 2, gate = w & 3;

    {   // stage both weight slices
        const f16* baseA = whh1 + ((size_t)branch << 18);
        const f16* baseB = wih1 + ((size_t)branch << 18);
        for (int c = tid; c < 8192; c += 512) {
            const int m2 = c >> 12;
            const int rl = (c & 4095) >> 6, coli = c & 63;
            const int gg = rl >> 4, f = (rl >> 3) & 1, ktp = rl & 7;
            const f16* src = (m2 ? baseB : baseA)
                + ((size_t)((gg * 16 + qm * 2 + f) * 8 + ktp) << 9) + coli * 8;
            *(uint4*)((m2 ? wldsB : wldsA) + rl * 512 + coli * 8) = *(const uint4*)src;
        }
    }
    ((uint4*)img)[tid] = (uint4){0u, 0u, 0u, 0u};   // 512 uint4 by 512 thr

    const float* bias = branch ? bR : bL;
    const int ubase = qm * 32 + (w < 2 ? w : 0) * 16 + fr;
    float bv[4];
#pragma unroll
    for (int g4 = 0; g4 < 4; ++g4) bv[g4] = bias[g4 * 256 + ubase];
    float cst[4] = {0.f, 0.f, 0.f, 0.f};
    const f16* gimg2 = h0img + (size_t)g * (NCLS * 4096);
    f16* gring = ring + (size_t)g * (4 * 4096);
    int* flgb = flags + g * 8 * 64;
    const f16* wmy = role ? wldsB : wldsA;

    f16x4 af[16];
    if (role) {                              // prefetch h0(0) frags via LLC
        const u64* s2 = (const u64*)gimg2 + l;
#pragma unroll
        for (int kt = 0; kt < 16; ++kt)
            af[kt] = __builtin_bit_cast(f16x4, ld_llc(s2 + kt * 64));
    }
    __syncthreads();

    for (int t = 0; t < NCLS; ++t) {
        if (!role) {
#pragma unroll
            for (int kt = 0; kt < 16; ++kt)
                af[kt] = *(const f16x4*)(img + kt * 256 + l * 4);
        }
        f32x4 acc[2];
#pragma unroll
        for (int f = 0; f < 2; ++f) {
            f32x4 a0 = {0.f,0.f,0.f,0.f}, a1 = {0.f,0.f,0.f,0.f};
#pragma unroll
            for (int ktp = 0; ktp < 8; ++ktp) {
                const f16x8 v = *(const f16x8*)(wmy + (((gate * 2 + f) * 8 + ktp) << 9) + l * 8);
                a0 = __builtin_amdgcn_mfma_f32_16x16x16f16(af[2 * ktp],     LO(v), a0, 0, 0, 0);
                a1 = __builtin_amdgcn_mfma_f32_16x16x16f16(af[2 * ktp + 1], HI(v), a1, 0, 0, 0);
            }
            acc[f] = a0 + a1;
        }
#pragma unroll
        for (int f = 0; f < 2; ++f)
#pragma unroll
            for (int r = 0; r < 4; ++r)
                cmb[((f * 4 + r) * 64 + l) * 9 + w] = acc[f][r];
        __syncthreads();                    // cmb ready; img af-reads done
        if (w < 2) {                        // finisher: frag f = w
            float hn[4];
#pragma unroll
            for (int r = 0; r < 4; ++r) {
                const int ci = ((w * 4 + r) * 64 + l) * 9;
                const float pi = cmb[ci + 0] + cmb[ci + 4] + bv[0];
                const float pf = cmb[ci + 1] + cmb[ci + 5] + bv[1];
                const float pg = cmb[ci + 2] + cmb[ci + 6] + bv[2];
                const float po = cmb[ci + 3] + cmb[ci + 7] + bv[3];
                const float ig = sigf(pi), fg = sigf(pf), gg = tanh_f(pg), og = sigf(po);
                cst[r] = fmaf(fg, cst[r], ig * gg);
                hn[r] = og * tanh_f(cst[r]);
            }
            if (t == NCLS - 1) {
#pragma unroll
                for (int r = 0; r < 4; ++r)
                    h1out[((size_t)(branch * NBATCH + tb * 16 + fq * 4 + r)) * NHID
                          + qm * 32 + w * 16 + fr] = hn[r];
            } else {
#pragma unroll
                for (int r = 0; r < 4; ++r)
                    img[(qm * 2 + w) * 256 + (fq * 4 + r + 16 * (fr >> 2)) * 4 + (fr & 3)] = (f16)hn[r];
            }
        }
        if (t == NCLS - 1) break;
        __syncthreads();                    // own 1 KB chunk complete in LDS
        f16* gdst = gring + (size_t)(t & 3) * 4096;
        if (w == 0) {                       // push chunk via sc1/LLC
            u64* gd = (u64*)gdst;
            st_llc(gd + qm * 128 + l,      ((const u64*)img)[qm * 128 + l]);
            st_llc(gd + qm * 128 + 64 + l, ((const u64*)img)[qm * 128 + 64 + l]);
            asm volatile("s_waitcnt vmcnt(0)" ::: "memory");   // chunk at LLC
            if (l == 0)
                __hip_atomic_store(flgb + qm * 64, t + 1, __ATOMIC_RELAXED, __HIP_MEMORY_SCOPE_AGENT);
        }
        if (role) {                          // prefetch h0(t+1) frags via LLC
            const u64* s2 = (const u64*)(gimg2 + (size_t)(t + 1) * 4096) + l;
#pragma unroll
            for (int kt = 0; kt < 16; ++kt)
                af[kt] = __builtin_bit_cast(f16x4, ld_llc(s2 + kt * 64));
        }
        if (w == 0 && l < 7) {
            const int p = l + (l >= qm);
            while (__hip_atomic_load(flgb + p * 64, __ATOMIC_RELAXED, __HIP_MEMORY_SCOPE_AGENT) <= t)
                __builtin_amdgcn_s_sleep(1);
        }
        __syncthreads();                    // peers ready
        if (tid < 128) {                    // gather 7 KB from LLC
            u64 tmp[7];
            const u64* gs = (const u64*)gdst;
#pragma unroll
            for (int j = 0; j < 7; ++j) {
                const int p = j + (j >= qm);
                tmp[j] = ld_llc(gs + p * 128 + tid);
            }
#pragma unroll
            for (int j = 0; j < 7; ++j) {
                const int p = j + (j >= qm);
                ((u64*)img)[p * 128 + tid] = tmp[j];
            }
        }
        __syncthreads();                    // img(t) complete
    }
}

// ---------------- K4: MLP head (2H -> 200 -> 128), f32 ------------------------
__global__ __launch_bounds__(256) void k_mlp(
    const float* __restrict__ h1all,   // [2][256][256]
    const float* __restrict__ W1, const float* __restrict__ b1,
    const float* __restrict__ W2, const float* __restrict__ b2,
    float* __restrict__ out)
{
    __shared__ float hrow[512];
    __shared__ float hid[200];
    const int b = blockIdx.x, tid = threadIdx.x;
    hrow[tid]       = h1all[(size_t)b * NHID + tid];
    hrow[256 + tid] = h1all[(size_t)(NBATCH + b) * NHID + tid];
    __syncthreads();
    if (tid < 200) {
        float a = b1[tid];
        const float* wr = W1 + (size_t)tid * 512;
        for (int k = 0; k < 512; ++k) a = fmaf(wr[k], hrow[k], a);
        hid[tid] = fmaxf(a, 0.f);
    }
    __syncthreads();
    if (tid < 128) {
        float a = b2[tid];
        const float* wr = W2 + (size_t)tid * 200;
        for (int j = 0; j < 200; ++j) a = fmaf(wr[j], hid[j], a);
        out[(size_t)b * 128 + tid] = a;
    }
}

// ---------------- launch ------------------------------------------------------
extern "C" void kernel_launch(void* const* d_in, const int* in_sizes, int n_in,
                              void* d_out, int out_size, void* d_ws, size_t ws_size,
                              hipStream_t stream)
{
    (void)in_sizes; (void)n_in; (void)out_size; (void)ws_size;
    const int*   ln    = (const int*)d_in[0];
    const int*   rn    = (const int*)d_in[2];
    const float* tlW   = (const float*)d_in[4];
    const float* tlU   = (const float*)d_in[5];
    const float* tlb   = (const float*)d_in[6];
    const float* trW   = (const float*)d_in[7];
    const float* trU   = (const float*)d_in[8];
    const float* trb   = (const float*)d_in[9];
    const float* wih0L = (const float*)d_in[10];
    const float* b0L   = (const float*)d_in[12];
    const float* b1L   = (const float*)d_in[15];
    const float* wih0R = (const float*)d_in[16];
    const float* b0R   = (const float*)d_in[18];
    const float* b1R   = (const float*)d_in[21];
    const float* mW1   = (const float*)d_in[22];
    const float* mb1   = (const float*)d_in[23];
    const float* mW2   = (const float*)d_in[24];
    const float* mb2   = (const float*)d_in[25];

    // workspace layout (bytes)
    char* ws = (char*)d_ws;
    f16*   w16    = (f16*)ws;                        // 3 MB swizzled weights
    float* states = (float*)(ws + 3145728);          // 256 KB
    float* h1out  = (float*)(ws + 3407872);          // 512 KB
    int*   flags  = (int*)(ws + 3932160);            // 128 KB (2 x 32 x 8 x 64 ints)
    f16*   h1ring = (f16*)(ws + 4063232);            // 1 MB
    f16*   h0img  = (f16*)(ws + 5111808);            // 32 MB

    f16* whh0 = w16;
    f16* whh1 = w16 + 2 * 262144;
    f16* wih1 = w16 + 4 * 262144;
    int* flags0 = flags;
    int* flags1 = flags + 16384;

    (void)hipFuncSetAttribute(reinterpret_cast<const void*>(k_rec0),
                              hipFuncAttributeMaxDynamicSharedMemorySize, 92160);
    (void)hipFuncSetAttribute(reinterpret_cast<const void*>(k_rec1),
                              hipFuncAttributeMaxDynamicSharedMemorySize, 157696);

    P6 p { (const float*)d_in[11], (const float*)d_in[17],   // nl_Whh0, nr_Whh0
           (const float*)d_in[14], (const float*)d_in[20],   // nl_Whh1, nr_Whh1
           (const float*)d_in[13], (const float*)d_in[19] }; // nl_Wih1, nr_Wih1
    k_zero<<<32, 1024, 0, stream>>>(flags);
    k_cvt<<<6144, 256, 0, stream>>>(p, w16);
    k_scalar_lstm<<<512, 128, 0, stream>>>(ln, rn, tlW, tlU, tlb, trW, trU, trb, states);
    k_rec0<<<256, 256, 92160, stream>>>(states, whh0, wih0L, wih0R, b0L, b0R, h0img, flags0);
    k_rec1<<<256, 512, 157696, stream>>>(whh1, wih1, h0img, b1L, b1R, h1ring, flags1, h1out);
    k_mlp<<<256, 256, 0, stream>>>(h1out, mW1, mb1, mW2, mb2, (float*)d_out);
}

// Round 10
// 820.589 us; speedup vs baseline: 17.5612x; 1.0901x over previous
//
#include <hip/hip_runtime.h>

// VoiceModel: 2 branches x { scalar-LSTM(1->1,L2) over T=512 per (b,class),
// then LSTM(1->256,L2) over 128 class-steps }, concat -> MLP(512->200->128).
// Round 10: FUSED two-layer recurrence kernel. 256 blocks (1/CU), 384 thr:
// waves 0-1 = layer0 (Whh0 LDS), 2-3 = layer1-recurrent (Whh1 LDS, lag 1 step),
// 4-5 = layer1-input (Wih1 streamed L2, reads h0 image block-locally).
// One exchange round per step (129 total vs 256 before), round-9 relaxed-sc1
// protocol unchanged.

typedef _Float16 f16;
typedef __attribute__((ext_vector_type(4))) _Float16 f16x4;
typedef __attribute__((ext_vector_type(8))) _Float16 f16x8;
typedef __attribute__((ext_vector_type(4))) float f32x4;
typedef unsigned long long u64;

#define NBATCH 256
#define NTIME  512
#define NCLS   128
#define NHID   256

__device__ __forceinline__ float sigf(float x) {
    return __builtin_amdgcn_rcpf(1.0f + __expf(-x));
}
__device__ __forceinline__ float tanh_f(float x) {
    return fmaf(2.0f, __builtin_amdgcn_rcpf(1.0f + __expf(-2.0f * x)), -1.0f);
}
__device__ __forceinline__ f16x4 LO(f16x8 v) { f16x4 r; r[0]=v[0]; r[1]=v[1]; r[2]=v[2]; r[3]=v[3]; return r; }
__device__ __forceinline__ f16x4 HI(f16x8 v) { f16x4 r; r[0]=v[4]; r[1]=v[5]; r[2]=v[6]; r[3]=v[7]; return r; }

// LLC-coherent (sc1) 8B ops: relaxed agent atomics, no cache maintenance.
__device__ __forceinline__ u64 ld_llc(const u64* p) {
    return __hip_atomic_load(p, __ATOMIC_RELAXED, __HIP_MEMORY_SCOPE_AGENT);
}
__device__ __forceinline__ void st_llc(u64* p, u64 v) {
    __hip_atomic_store(p, v, __ATOMIC_RELAXED, __HIP_MEMORY_SCOPE_AGENT);
}

// ---------------- K0: convert + swizzle 6 weight matrices (1024x256) to f16 --
// layout per matrix: elem ((g*16+fi)*8+ktp)*512 + l*8 + e   (l = lane)
//   = W[g*256 + fi*16 + fr][ktp*32 + (e>>2)*16 + fq*4 + (e&3)]
struct P6 {
    const float* s0; const float* s1; const float* s2;
    const float* s3; const float* s4; const float* s5;
};

__global__ __launch_bounds__(256) void k_cvt(P6 p, f16* __restrict__ dst) {
    int i = blockIdx.x * 256 + threadIdx.x;      // 6 * 262144 total
    int seg = i >> 18, d = i & 262143;
    const float* s = seg == 0 ? p.s0 : seg == 1 ? p.s1 : seg == 2 ? p.s2
                   : seg == 3 ? p.s3 : seg == 4 ? p.s4 : p.s5;
    const int e  = d & 7;
    const int fr = (d >> 3) & 15;
    const int fq = (d >> 7) & 3;
    const int ktp = (d >> 9) & 7;
    const int fi = (d >> 12) & 15;
    const int g  = (d >> 16) & 3;
    const int row = g * 256 + fi * 16 + fr;
    const int col = ktp * 32 + (e >> 2) * 16 + fq * 4 + (e & 3);
    dst[i] = (f16)s[row * 256 + col];
}

// ---------------- zero the exchange flags (every call; graph-replay safe) ----
__global__ void k_zero(int* __restrict__ f) { f[blockIdx.x * 1024 + threadIdx.x] = 0; }

// ---------------- K1: scalar 2-layer LSTM per (branch, b, class) -------------
__global__ __launch_bounds__(128) void k_scalar_lstm(
    const int* __restrict__ ln, const int* __restrict__ rn,
    const float* __restrict__ tlW, const float* __restrict__ tlU, const float* __restrict__ tlb,
    const float* __restrict__ trW, const float* __restrict__ trU, const float* __restrict__ trb,
    float* __restrict__ states)
{
    __shared__ int tok[NTIME];
    const int bid = blockIdx.x;
    const int branch = bid >> 8;
    const int b = bid & 255;
    const int* tp = (branch ? rn : ln) + (size_t)b * (4 * NTIME);  // voice 0
    for (int i = threadIdx.x; i < NTIME; i += 128) tok[i] = tp[i];
    __syncthreads();
    const float* W  = branch ? trW : tlW;
    const float* U  = branch ? trU : tlU;
    const float* Bb = branch ? trb : tlb;
    const float u00 = U[0], u01 = U[1], u02 = U[2], u03 = U[3];
    const float f00 = Bb[0], f01 = Bb[1], f02 = Bb[2], f03 = Bb[3];
    const float o00 = f00 + W[0], o01 = f01 + W[1], o02 = f02 + W[2], o03 = f03 + W[3];
    const float w10 = W[4], w11 = W[5], w12 = W[6], w13 = W[7];
    const float u10 = U[4], u11 = U[5], u12 = U[6], u13 = U[7];
    const float b10 = Bb[4], b11 = Bb[5], b12 = Bb[6], b13 = Bb[7];
    const int n = threadIdx.x;
    float h0 = 0.f, c0 = 0.f, h1 = 0.f, c1 = 0.f;
    for (int t = 0; t < NTIME; ++t) {
        const bool x = (tok[t] == n);
        float pi = fmaf(u00, h0, x ? o00 : f00);
        float pf = fmaf(u01, h0, x ? o01 : f01);
        float pg = fmaf(u02, h0, x ? o02 : f02);
        float po = fmaf(u03, h0, x ? o03 : f03);
        float ig = sigf(pi), fg = sigf(pf), gg = tanh_f(pg), og = sigf(po);
        c0 = fmaf(fg, c0, ig * gg);
        h0 = og * tanh_f(c0);
        pi = fmaf(w10, h0, fmaf(u10, h1, b10));
        pf = fmaf(w11, h0, fmaf(u11, h1, b11));
        pg = fmaf(w12, h0, fmaf(u12, h1, b12));
        po = fmaf(w13, h0, fmaf(u13, h1, b13));
        ig = sigf(pi); fg = sigf(pf); gg = tanh_f(pg); og = sigf(po);
        c1 = fmaf(fg, c1, ig * gg);
        h1 = og * tanh_f(c1);
    }
    states[((size_t)(branch * NBATCH + b)) * NCLS + n] = h1;
}

// ---------------- K2: FUSED 2-layer recurrence -------------------------------
// grid 256 = member qm(8) * 32 + group(32). 384 thr = 6 waves.
// role = w>>1: 0 = layer0, 1 = layer1-recurrent, 2 = layer1-input.
// f = w&1: fragment; block owns hidden frags {qm*2, qm*2+1} of both layers.
// Pipeline: step s computes h0(s) [roles 0] and h1(s-1) [roles 1+2].
// Exchange both 1KB image chunks per step with ONE flag round (relaxed sc1).
__global__ __launch_bounds__(384, 1) void k_rec(
    const float* __restrict__ states,
    const f16* __restrict__ whh0, const f16* __restrict__ whh1,
    const f16* __restrict__ wih1,
    const float* __restrict__ wih0L, const float* __restrict__ wih0R,
    const float* __restrict__ b0L, const float* __restrict__ b0R,
    const float* __restrict__ b1L, const float* __restrict__ b1R,
    f16* __restrict__ h0img,               // [32 group][128 s][4096] exchange h0
    f16* __restrict__ ring,                // [32 group][4 slot][4096] exchange h1
    int* __restrict__ flags,               // [32 group][8 member] stride 64 ints
    float* __restrict__ h1out)             // [2][256][256] f32
{
    extern __shared__ char smem[];
    f16*   wlds0 = (f16*)smem;                   // 65536 B Whh0 slice
    f16*   wlds1 = (f16*)(smem + 65536);         // 65536 B Whh1 slice
    f16*   img0  = (f16*)(smem + 131072);        // 8192 B h0 image
    f16*   img1  = (f16*)(smem + 139264);        // 8192 B h1 image
    float* cmb   = (float*)(smem + 147456);      // 8192 B [2 f][4 g][4 r][64 l]

    const int qm = blockIdx.x >> 5, g = blockIdx.x & 31;
    const int branch = g >> 4, tb = g & 15;
    const int tid = threadIdx.x;
    const int w = tid >> 6, l = tid & 63, fr = l & 15, fq = l >> 4;
    const int role = w >> 1, f = w & 1;
    const int fi = qm * 2 + f;

    {   // stage Whh0 + Whh1 slices (64 rows x 512 f16 each)
        const f16* baseA = whh0 + ((size_t)branch << 18);
        const f16* baseB = whh1 + ((size_t)branch << 18);
        for (int c = tid; c < 8192; c += 384) {
            const int m2 = c >> 12;
            const int rl = (c & 4095) >> 6, coli = c & 63;
            const int gg = rl >> 4, ff = (rl >> 3) & 1, ktp = rl & 7;
            const f16* src = (m2 ? baseB : baseA)
                + ((size_t)((gg * 16 + qm * 2 + ff) * 8 + ktp) << 9) + coli * 8;
            *(uint4*)((m2 ? wlds1 : wlds0) + rl * 512 + coli * 8) = *(const uint4*)src;
        }
    }
    for (int i = tid; i < 512; i += 384) {
        ((uint4*)img0)[i] = (uint4){0u, 0u, 0u, 0u};
        ((uint4*)img1)[i] = (uint4){0u, 0u, 0u, 0u};
    }

    float bv[4], w0v[4];
    {
        const float* b0 = branch ? b0R : b0L;
        const float* b1 = branch ? b1R : b1L;
        const float* w0p = branch ? wih0R : wih0L;
#pragma unroll
        for (int g4 = 0; g4 < 4; ++g4) {
            const int row = g4 * 256 + fi * 16 + fr;
            bv[g4]  = (role == 0) ? b0[row] : b1[row];
            w0v[g4] = (role == 0) ? w0p[row] : 0.f;
        }
    }
    float cst[4] = {0.f, 0.f, 0.f, 0.f};
    const f16* wstream = wih1 + ((size_t)branch << 18) + l * 8;
    f16* gimg = h0img + (size_t)g * (NCLS * 4096);
    f16* gring = ring + (size_t)g * (4 * 4096);
    int* flgb = flags + g * 512;
    __syncthreads();

    for (int s = 0; s <= NCLS; ++s) {
        f16* gslot = gring + (size_t)(s & 3) * 4096;
        // ---- phase 1: compute (+ cmb publish by role 2) --------------------
        f32x4 acc[4];
#pragma unroll
        for (int g4 = 0; g4 < 4; ++g4) { f32x4 z = {0.f,0.f,0.f,0.f}; acc[g4] = z; }
        float st[4] = {0.f, 0.f, 0.f, 0.f};
        const bool active = (role == 0) ? (s < NCLS) : (s > 0);
        if (active) {
            f16x4 af[16];
            const f16* srcimg = (role == 1) ? img1 : img0;
#pragma unroll
            for (int kt = 0; kt < 16; ++kt)
                af[kt] = *(const f16x4*)(srcimg + kt * 256 + l * 4);
            if (role == 2) {
#pragma unroll
                for (int g4 = 0; g4 < 4; ++g4) {
                    f16x8 wv[8];
#pragma unroll
                    for (int ktp = 0; ktp < 8; ++ktp)
                        wv[ktp] = *(const f16x8*)(wstream + ((size_t)((g4 * 16 + fi) * 8 + ktp) << 9));
#pragma unroll
                    for (int ktp = 0; ktp < 8; ++ktp) {
                        acc[g4] = __builtin_amdgcn_mfma_f32_16x16x16f16(af[2*ktp],   LO(wv[ktp]), acc[g4], 0, 0, 0);
                        acc[g4] = __builtin_amdgcn_mfma_f32_16x16x16f16(af[2*ktp+1], HI(wv[ktp]), acc[g4], 0, 0, 0);
                    }
                }
#pragma unroll
                for (int g4 = 0; g4 < 4; ++g4)
#pragma unroll
                    for (int r = 0; r < 4; ++r)
                        cmb[(f * 16 + g4 * 4 + r) * 64 + l] = acc[g4][r];
            } else {
                const f16* wl = role ? wlds1 : wlds0;
#pragma unroll
                for (int g4 = 0; g4 < 4; ++g4)
#pragma unroll
                    for (int ktp = 0; ktp < 8; ++ktp) {
                        const f16x8 v = *(const f16x8*)(wl + (((g4 * 2 + f) * 8 + ktp) << 9) + l * 8);
                        acc[g4] = __builtin_amdgcn_mfma_f32_16x16x16f16(af[2*ktp],   LO(v), acc[g4], 0, 0, 0);
                        acc[g4] = __builtin_amdgcn_mfma_f32_16x16x16f16(af[2*ktp+1], HI(v), acc[g4], 0, 0, 0);
                    }
                if (role == 0) {
#pragma unroll
                    for (int r = 0; r < 4; ++r)
                        st[r] = states[((size_t)(branch * NBATCH + tb * 16 + fq * 4 + r)) * NCLS + s];
                }
            }
        }
        __syncthreads();                    // cmb ready; img reads done
        // ---- phase 3: finish + push ----------------------------------------
        if (role == 0 && s < NCLS) {
#pragma unroll
            for (int r = 0; r < 4; ++r) {
                const float pi = fmaf(st[r], w0v[0], acc[0][r] + bv[0]);
                const float pf = fmaf(st[r], w0v[1], acc[1][r] + bv[1]);
                const float pg = fmaf(st[r], w0v[2], acc[2][r] + bv[2]);
                const float po = fmaf(st[r], w0v[3], acc[3][r] + bv[3]);
                const float ig = sigf(pi), fg = sigf(pf), gg = tanh_f(pg), og = sigf(po);
                cst[r] = fmaf(fg, cst[r], ig * gg);
                const float hn = og * tanh_f(cst[r]);
                img0[fi * 256 + (fq * 4 + r + 16 * (fr >> 2)) * 4 + (fr & 3)] = (f16)hn;
            }
            asm volatile("s_waitcnt lgkmcnt(0)" ::: "memory");
            st_llc((u64*)(gimg + (size_t)s * 4096) + fi * 64 + l,
                   ((const u64*)img0)[fi * 64 + l]);
            asm volatile("s_waitcnt vmcnt(0)" ::: "memory");
        } else if (role == 1) {
            if (s > 0) {
                float hn[4];
#pragma unroll
                for (int r = 0; r < 4; ++r) {
                    const float pi = acc[0][r] + cmb[(f * 16 + 0 + r) * 64 + l] + bv[0];
                    const float pf = acc[1][r] + cmb[(f * 16 + 4 + r) * 64 + l] + bv[1];
                    const float pg = acc[2][r] + cmb[(f * 16 + 8 + r) * 64 + l] + bv[2];
                    const float po = acc[3][r] + cmb[(f * 16 + 12 + r) * 64 + l] + bv[3];
                    const float ig = sigf(pi), fg = sigf(pf), gg = tanh_f(pg), og = sigf(po);
                    cst[r] = fmaf(fg, cst[r], ig * gg);
                    hn[r] = og * tanh_f(cst[r]);
                }
                if (s == NCLS) {
#pragma unroll
                    for (int r = 0; r < 4; ++r)
                        h1out[((size_t)(branch * NBATCH + tb * 16 + fq * 4 + r)) * NHID
                              + fi * 16 + fr] = hn[r];
                } else {
#pragma unroll
                    for (int r = 0; r < 4; ++r)
                        img1[fi * 256 + (fq * 4 + r + 16 * (fr >> 2)) * 4 + (fr & 3)] = (f16)hn[r];
                }
            }
            if (s < NCLS) {                 // push h1(s-1) chunk (zeros at s=0)
                asm volatile("s_waitcnt lgkmcnt(0)" ::: "memory");
                st_llc((u64*)gslot + fi * 64 + l, ((const u64*)img1)[fi * 64 + l]);
                asm volatile("s_waitcnt vmcnt(0)" ::: "memory");
            }
        }
        if (s == NCLS) break;
        __syncthreads();                    // all pushes drained (per-wave vmcnt)
        if (w == 0) {
            if (l == 0)
                __hip_atomic_store(flgb + qm * 64, s + 1, __ATOMIC_RELAXED, __HIP_MEMORY_SCOPE_AGENT);
            if (l < 7) {
                const int p = l + (l >= qm);
                while (__hip_atomic_load(flgb + p * 64, __ATOMIC_RELAXED, __HIP_MEMORY_SCOPE_AGENT) <= s)
                    __builtin_amdgcn_s_sleep(1);
            }
        }
        __syncthreads();                    // peers ready
        if (tid < 128) {                    // gather 7 KB of h0(s)
            const u64* gs = (const u64*)(gimg + (size_t)s * 4096);
            u64 tmp[7];
#pragma unroll
            for (int j = 0; j < 7; ++j) {
                const int p = j + (j >= qm);
                tmp[j] = ld_llc(gs + p * 128 + tid);
            }
#pragma unroll
            for (int j = 0; j < 7; ++j) {
                const int p = j + (j >= qm);
                ((u64*)img0)[p * 128 + tid] = tmp[j];
            }
        } else if (tid < 256) {             // gather 7 KB of h1(s-1)
            const int t2 = tid - 128;
            const u64* gs = (const u64*)gslot;
            u64 tmp[7];
#pragma unroll
            for (int j = 0; j < 7; ++j) {
                const int p = j + (j >= qm);
                tmp[j] = ld_llc(gs + p * 128 + t2);
            }
#pragma unroll
            for (int j = 0; j < 7; ++j) {
                const int p = j + (j >= qm);
                ((u64*)img1)[p * 128 + t2] = tmp[j];
            }
        }
        __syncthreads();                    // images complete for step s+1
    }
}

// ---------------- K4: MLP head (2H -> 200 -> 128), f32 ------------------------
__global__ __launch_bounds__(256) void k_mlp(
    const float* __restrict__ h1all,   // [2][256][256]
    const float* __restrict__ W1, const float* __restrict__ b1,
    const float* __restrict__ W2, const float* __restrict__ b2,
    float* __restrict__ out)
{
    __shared__ float hrow[512];
    __shared__ float hid[200];
    const int b = blockIdx.x, tid = threadIdx.x;
    hrow[tid]       = h1all[(size_t)b * NHID + tid];
    hrow[256 + tid] = h1all[(size_t)(NBATCH + b) * NHID + tid];
    __syncthreads();
    if (tid < 200) {
        float a = b1[tid];
        const float* wr = W1 + (size_t)tid * 512;
        for (int k = 0; k < 512; ++k) a = fmaf(wr[k], hrow[k], a);
        hid[tid] = fmaxf(a, 0.f);
    }
    __syncthreads();
    if (tid < 128) {
        float a = b2[tid];
        const float* wr = W2 + (size_t)tid * 200;
        for (int j = 0; j < 200; ++j) a = fmaf(wr[j], hid[j], a);
        out[(size_t)b * 128 + tid] = a;
    }
}

// ---------------- launch ------------------------------------------------------
extern "C" void kernel_launch(void* const* d_in, const int* in_sizes, int n_in,
                              void* d_out, int out_size, void* d_ws, size_t ws_size,
                              hipStream_t stream)
{
    (void)in_sizes; (void)n_in; (void)out_size; (void)ws_size;
    const int*   ln    = (const int*)d_in[0];
    const int*   rn    = (const int*)d_in[2];
    const float* tlW   = (const float*)d_in[4];
    const float* tlU   = (const float*)d_in[5];
    const float* tlb   = (const float*)d_in[6];
    const float* trW   = (const float*)d_in[7];
    const float* trU   = (const float*)d_in[8];
    const float* trb   = (const float*)d_in[9];
    const float* wih0L = (const float*)d_in[10];
    const float* b0L   = (const float*)d_in[12];
    const float* b1L   = (const float*)d_in[15];
    const float* wih0R = (const float*)d_in[16];
    const float* b0R   = (const float*)d_in[18];
    const float* b1R   = (const float*)d_in[21];
    const float* mW1   = (const float*)d_in[22];
    const float* mb1   = (const float*)d_in[23];
    const float* mW2   = (const float*)d_in[24];
    const float* mb2   = (const float*)d_in[25];

    // workspace layout (bytes)
    char* ws = (char*)d_ws;
    f16*   w16    = (f16*)ws;                        // 3 MB swizzled weights
    float* states = (float*)(ws + 3145728);          // 256 KB
    float* h1out  = (float*)(ws + 3407872);          // 512 KB
    int*   flags  = (int*)(ws + 3932160);            // 64 KB (32 x 8 x 64 ints)
    f16*   h1ring = (f16*)(ws + 4063232);            // 1 MB
    f16*   h0img  = (f16*)(ws + 5111808);            // 32 MB

    f16* whh0 = w16;
    f16* whh1 = w16 + 2 * 262144;
    f16* wih1 = w16 + 4 * 262144;

    (void)hipFuncSetAttribute(reinterpret_cast<const void*>(k_rec),
                              hipFuncAttributeMaxDynamicSharedMemorySize, 155648);

    P6 p { (const float*)d_in[11], (const float*)d_in[17],   // nl_Whh0, nr_Whh0
           (const float*)d_in[14], (const float*)d_in[20],   // nl_Whh1, nr_Whh1
           (const float*)d_in[13], (const float*)d_in[19] }; // nl_Wih1, nr_Wih1
    k_zero<<<16, 1024, 0, stream>>>(flags);
    k_cvt<<<6144, 256, 0, stream>>>(p, w16);
    k_scalar_lstm<<<512, 128, 0, stream>>>(ln, rn, tlW, tlU, tlb, trW, trU, trb, states);
    k_rec<<<256, 384, 155648, stream>>>(states, whh0, whh1, wih1, wih0L, wih0R,
                                        b0L, b0R, b1L, b1R, h0img, h1ring, flags, h1out);
    k_mlp<<<256, 256, 0, stream>>>(h1out, mW1, mb1, mW2, mb2, (float*)d_out);
}